// Round 3
// baseline (12012.269 us; speedup 1.0000x reference)
//
#include <hip/hip_runtime.h>
#include <stdint.h>

// RevGRU encoder, MI355X.
// R9: R8 (4-hop + sentinel gates + XCD colocation, 8.74ms) with latency overlap:
//  (1) SPECULATIVE STAGING: issue the one-shot tagged data loads BEFORE the
//      sentinel poll; verify tags after the gate barrier and retry only stale
//      slots (the existing backstop). Data latency hides under sentinel wait.
//      Applied to all 4 scan phases, q reads, and producer h0s staging.
//  (2) L1 X1 PREFETCH: batch-issue the 6 per-step x1r reads at step top
//      (producers run up to 24 steps ahead, tags usually valid), verify once
//      after the z1 MFMA barrier. Removes ~6 serial L3 round trips from the
//      rate-limiting L1 loop.
//  (3) __launch_bounds__(512,1): 112 WGs on 256 CUs = 1 WG/CU regardless;
//      don't cap VGPR at 128 (spec staging needs ~30 transient regs).

typedef __attribute__((ext_vector_type(8))) short short8;
typedef __attribute__((ext_vector_type(4))) float floatx4;

#define MFMA16(a,b,c) __builtin_amdgcn_mfma_f32_16x16x32_bf16((a),(b),(c),0,0,0)

__device__ __forceinline__ short bf16_rne(float f) {
  uint32_t u = __float_as_uint(f);
  u += 0x7FFFu + ((u >> 16) & 1u);
  return (short)(u >> 16);
}
__device__ __forceinline__ float bf16f(short s) {
  return __uint_as_float(((uint32_t)(uint16_t)s) << 16);
}
__device__ __forceinline__ void st64(unsigned long long* p, unsigned long long v) {
  __hip_atomic_store(p, v, __ATOMIC_RELAXED, __HIP_MEMORY_SCOPE_AGENT);
}
__device__ __forceinline__ unsigned long long ld64(const unsigned long long* p) {
  return __hip_atomic_load(p, __ATOMIC_RELAXED, __HIP_MEMORY_SCOPE_AGENT);
}

#define SCALE_F 8388608.0f
#define INV_S   (1.0f/8388608.0f)

// ---- static device scratch ----
__device__ float g_X[50331648];            // X0: 32768 x 1536 (layer-0 x-projections)
__device__ short g_WTh[2][786432];         // per-layer x-proj weights, transposed, split hi
__device__ short g_WTl[2][786432];         // split lo
__device__ float g_biasL[2][1536];
__device__ unsigned long long g_ch[2][4][6][4096];  // per-layer scan channels
__device__ unsigned long long g_h0s[16777216];      // [t][row][col] tagged {tag, f32 h0f}
__device__ unsigned long long g_x1r[3145728];       // ring [t&31][row][1536] tagged {tag, f32}
__device__ unsigned long long g_sent[2][4][4][8];   // sentinels [L][dm][phase][cg]
__device__ unsigned g_epoch;

__global__ void bump_epoch() { g_epoch = g_epoch + 1u; }

// ------------------------------------------------------------------
__global__ void prep_x(const float* __restrict__ Wz1, const float* __restrict__ bz1,
                       const float* __restrict__ Wg1, const float* __restrict__ bg1,
                       const float* __restrict__ Wz2, const float* __restrict__ bz2,
                       const float* __restrict__ Wg2, const float* __restrict__ bg2,
                       int layer, int* __restrict__ d_out, int zero_extra) {
  int idx = blockIdx.x * 256 + threadIdx.x;   // grid covers 512*1536 exactly
  int k = idx / 1536;
  int c = idx - k * 1536;
  const float* W; const float* bb; int cc; int ncols;
  if (c < 512)       { W = Wz1; bb = bz1; cc = c;        ncols = 512; }
  else if (c < 768)  { W = Wg1; bb = bg1; cc = c - 512;  ncols = 256; }
  else if (c < 1280) { W = Wz2; bb = bz2; cc = c - 768;  ncols = 512; }
  else               { W = Wg2; bb = bg2; cc = c - 1280; ncols = 256; }
  float wv = W[(size_t)layer * 768 * ncols + (size_t)k * ncols + cc];
  short hi = bf16_rne(wv);
  short lo = bf16_rne(wv - bf16f(hi));
  g_WTh[layer][(size_t)c * 512 + k] = hi;
  g_WTl[layer][(size_t)c * 512 + k] = lo;
  if (k == 0) g_biasL[layer][c] = bb[layer * ncols + cc];
  if (zero_extra && idx < 6400) d_out[65536 + idx] = 0;   // saved[0] = h0 = zeros
}

// ------------------------------------------------------------------
__global__ __launch_bounds__(256)
void gemmx_kernel(const int* __restrict__ seq, const float* __restrict__ emb) {
  __shared__ float At[128][36];
  __shared__ short Bhi[128][40];
  __shared__ short Blo[128][40];
  __shared__ int toks[128];
  int tid = threadIdx.x;
  int r0 = blockIdx.x * 128;
  int c0 = blockIdx.y * 128;
  if (tid < 128) toks[tid] = seq[r0 + tid];
  int lane = tid & 63;
  int wid = tid >> 6;
  int wm = wid & 1, wn = wid >> 1;
  int lm = lane & 15, lq = lane >> 4;
  floatx4 zero4 = {0.f, 0.f, 0.f, 0.f};
  floatx4 acc[4][4];
#pragma unroll
  for (int a = 0; a < 4; ++a)
#pragma unroll
    for (int b = 0; b < 4; ++b) acc[a][b] = zero4;
  __syncthreads();
  int am = tid >> 1;
  int ah = (tid & 1) * 16;
  const float* arow = emb + (size_t)toks[am] * 512;
  const short* bh_base = g_WTh[0] + (size_t)(c0 + am) * 512;
  const short* bl_base = g_WTl[0] + (size_t)(c0 + am) * 512;
  for (int kb = 0; kb < 16; ++kb) {
    int k0 = kb * 32 + ah;
    float4 a0 = *(const float4*)(arow + k0);
    float4 a1 = *(const float4*)(arow + k0 + 4);
    float4 a2 = *(const float4*)(arow + k0 + 8);
    float4 a3 = *(const float4*)(arow + k0 + 12);
    short4 b0 = *(const short4*)(bh_base + k0);
    short4 b1 = *(const short4*)(bh_base + k0 + 4);
    short4 b2 = *(const short4*)(bh_base + k0 + 8);
    short4 b3 = *(const short4*)(bh_base + k0 + 12);
    short4 l0 = *(const short4*)(bl_base + k0);
    short4 l1 = *(const short4*)(bl_base + k0 + 4);
    short4 l2 = *(const short4*)(bl_base + k0 + 8);
    short4 l3 = *(const short4*)(bl_base + k0 + 12);
    __syncthreads();
    *(float4*)&At[am][ah]      = a0;
    *(float4*)&At[am][ah + 4]  = a1;
    *(float4*)&At[am][ah + 8]  = a2;
    *(float4*)&At[am][ah + 12] = a3;
    *(short4*)&Bhi[am][ah]      = b0;
    *(short4*)&Bhi[am][ah + 4]  = b1;
    *(short4*)&Bhi[am][ah + 8]  = b2;
    *(short4*)&Bhi[am][ah + 12] = b3;
    *(short4*)&Blo[am][ah]      = l0;
    *(short4*)&Blo[am][ah + 4]  = l1;
    *(short4*)&Blo[am][ah + 8]  = l2;
    *(short4*)&Blo[am][ah + 12] = l3;
    __syncthreads();
    short8 afh[4], afl[4];
#pragma unroll
    for (int mt = 0; mt < 4; ++mt) {
      const float* ap = &At[wm*64 + mt*16 + lm][lq*8];
#pragma unroll
      for (int j = 0; j < 8; ++j) {
        float v = ap[j];
        short hi = bf16_rne(v);
        afh[mt][j] = hi;
        afl[mt][j] = bf16_rne(v - bf16f(hi));
      }
    }
#pragma unroll
    for (int nt = 0; nt < 4; ++nt) {
      short8 bfh = *(short8*)&Bhi[wn*64 + nt*16 + lm][lq*8];
      short8 bfl = *(short8*)&Blo[wn*64 + nt*16 + lm][lq*8];
#pragma unroll
      for (int mt = 0; mt < 4; ++mt) {
        acc[mt][nt] = MFMA16(afh[mt], bfh, acc[mt][nt]);
        acc[mt][nt] = MFMA16(afl[mt], bfh, acc[mt][nt]);
        acc[mt][nt] = MFMA16(afh[mt], bfl, acc[mt][nt]);
      }
    }
  }
#pragma unroll
  for (int nt = 0; nt < 4; ++nt) {
    int gc = c0 + wn*64 + nt*16 + lm;
    float bv = g_biasL[0][gc];
#pragma unroll
    for (int mt = 0; mt < 4; ++mt) {
#pragma unroll
      for (int i = 0; i < 4; ++i) {
        int gr = r0 + wm*64 + mt*16 + lq*4 + i;
        g_X[(size_t)gr * 1536 + gc] = acc[mt][nt][i] + bv;
      }
    }
  }
}

// ------------------------------------------------------------------
__global__ __launch_bounds__(512, 1)
void fused_kernel(const float* __restrict__ Wz1g, const float* __restrict__ Wg1g,
                  const float* __restrict__ Wz2g, const float* __restrict__ Wg2g,
                  const int* __restrict__ lengths, int* __restrict__ d_out) {
  __shared__ int   h1i[16][260];
  __shared__ int   h2i[16][260];
  __shared__ short phi[16][264];
  __shared__ short pmi[16][264];
  __shared__ short plo[16][264];
  __shared__ float redbuf[2304];
  __shared__ int lens[16];
  __shared__ short ahs[16][520];
  __shared__ short als[16][520];

  int tid = threadIdx.x;
  int bid = blockIdx.x;
  int lane = tid & 63, wv = tid >> 6;   // 8 waves
  int lm = lane & 15, lq = lane >> 4;
  unsigned ep = g_epoch;

  if (bid >= 64) {
    // ================== role: X1 producer (48 WGs) ==================
    int xw = bid - 64;
    int r4 = xw & 3;        // row tile (16 rows) == dm of the L0 group it consumes
    int cs = xw >> 2;       // col slice (128 cols), 0..11
    int colx = cs * 128 + wv * 16 + lm;     // this lane's output column
    short8 bh[16], bl[16];
#pragma unroll
    for (int kf = 0; kf < 16; ++kf) {
      bh[kf] = *(const short8*)&g_WTh[1][(size_t)colx * 512 + kf * 32 + lq * 8];
      bl[kf] = *(const short8*)&g_WTl[1][(size_t)colx * 512 + kf * 32 + lq * 8];
    }
    float bvx = g_biasL[1][colx];
    int sr2 = tid >> 5;             // row 0..15
    int cb  = (tid & 31) * 16;      // 16 cols each

    for (int t = 0; t < 512; ++t) {
      unsigned tagt = (ep << 10) | (unsigned)(t + 1);
      // speculative stage of h0s[t] rows r4*16..+16, then gate, then verify
      {
        const unsigned long long* hp = &g_h0s[((size_t)(t * 64) + r4 * 16 + sr2) * 512 + cb];
        unsigned long long v[16];
#pragma unroll
        for (int i = 0; i < 16; ++i) v[i] = ld64(hp + i);
        if (tid < 8) {
          const unsigned long long* sp = &g_sent[0][r4][3][tid];
          while ((int)((unsigned)(ld64(sp) >> 32) - tagt) < 0) __builtin_amdgcn_s_sleep(2);
        }
        __syncthreads();
        unsigned pend = 0;
#pragma unroll
        for (int i = 0; i < 16; ++i)
          if ((unsigned)(v[i] >> 32) != tagt) pend |= 1u << i;
        while (pend) {
          __builtin_amdgcn_s_sleep(1);
#pragma unroll
          for (int i = 0; i < 16; ++i)
            if (pend & (1u << i)) {
              v[i] = ld64(hp + i);
              if ((unsigned)(v[i] >> 32) == tagt) pend &= ~(1u << i);
            }
        }
#pragma unroll
        for (int i = 0; i < 16; ++i) {
          float f = __uint_as_float((unsigned)v[i]);
          short hi = bf16_rne(f);
          ahs[sr2][cb + i] = hi;
          als[sr2][cb + i] = bf16_rne(f - bf16f(hi));
        }
      }
      __syncthreads();
      floatx4 acc = {0.f, 0.f, 0.f, 0.f};
#pragma unroll
      for (int kf = 0; kf < 16; ++kf) {
        short8 a0 = *(short8*)&ahs[lm][kf * 32 + lq * 8];
        short8 a1 = *(short8*)&als[lm][kf * 32 + lq * 8];
        acc = MFMA16(a0, bh[kf], acc);
        acc = MFMA16(a1, bh[kf], acc);
        acc = MFMA16(a0, bl[kf], acc);
      }
      // throttle: don't clobber ring slots L1 hasn't consumed (window 24 of 32)
      if (t >= 25) {
        if (tid < 4) {
          unsigned need = (ep << 10) | (unsigned)(t - 24);
          while ((unsigned)(ld64(&g_ch[1][tid][5][0]) >> 32) < need) __builtin_amdgcn_s_sleep(2);
        }
      }
      __syncthreads();
#pragma unroll
      for (int i = 0; i < 4; ++i) {
        int row = r4 * 16 + lq * 4 + i;
        st64(&g_x1r[((size_t)(t & 31) * 64 + row) * 1536 + colx],
             ((unsigned long long)tagt << 32) | __float_as_uint(acc[i] + bvx));
      }
      __syncthreads();   // before next stage overwrites ahs/als
    }
    return;
  }

  // ================== role: scan (layer L), 32 WGs each ==================
  // XCD colocation: the 8 cooperating WGs of a (L,dm) group share bid%8.
  int grp = bid & 7;
  int cg  = bid >> 3;     // column group 0..7
  int L   = grp >> 2;
  int dm  = grp & 3;      // batch domain 0..3
  int rb0 = dm * 16;
  unsigned long long (*ch)[4096] = g_ch[L][dm];

  if (tid < 16) lens[tid] = lengths[rb0 + tid];
  for (int i = tid; i < 16 * 260; i += 512) { ((int*)h1i)[i] = 0; ((int*)h2i)[i] = 0; }

  // ---- preload recurrent-weight B-frags into registers (split-bf16) ----
  short8 wz1a[4], wz1b[4], wz1c[4], wz2a[4], wz2b[4], wz2c[4];
  short8 wg1a[2], wg1b[2], wg2a[2], wg2b[2];
  {
    int nt = wv & 3, kh = wv >> 2;
    int colz = cg * 64 + nt * 16 + lm;
    const float* W1 = Wz1g + (size_t)L * 768 * 512 + (size_t)512 * 512 + colz;
    const float* W2 = Wz2g + (size_t)L * 768 * 512 + (size_t)512 * 512 + colz;
#pragma unroll
    for (int ks = 0; ks < 4; ++ks) {
      int k0 = kh * 128 + ks * 32 + lq * 8;
      short8 t0, t1, t2, u0, u1, u2;
#pragma unroll
      for (int j = 0; j < 8; ++j) {
        float v = W1[(size_t)(k0 + j) * 512] * INV_S;   // pre-scale: A is raw int h
        short a0 = bf16_rne(v); float r1 = v - bf16f(a0);
        short a1 = bf16_rne(r1); float r2 = r1 - bf16f(a1);
        t0[j] = a0; t1[j] = a1; t2[j] = bf16_rne(r2);
        float v2 = W2[(size_t)(k0 + j) * 512] * INV_S;
        short d0 = bf16_rne(v2); float s1 = v2 - bf16f(d0);
        short d1 = bf16_rne(s1); float s2 = s1 - bf16f(d1);
        u0[j] = d0; u1[j] = d1; u2[j] = bf16_rne(s2);
      }
      wz1a[ks] = t0; wz1b[ks] = t1; wz1c[ks] = t2;
      wz2a[ks] = u0; wz2b[ks] = u1; wz2c[ks] = u2;
    }
    int ntg = wv & 1, kq = wv >> 1;
    int colg = cg * 32 + ntg * 16 + lm;
    const float* G1 = Wg1g + (size_t)L * 768 * 256 + (size_t)512 * 256 + colg;
    const float* G2 = Wg2g + (size_t)L * 768 * 256 + (size_t)512 * 256 + colg;
#pragma unroll
    for (int ks = 0; ks < 2; ++ks) {
      int k0 = kq * 64 + ks * 32 + lq * 8;
      short8 t0, t1, u0, u1;
#pragma unroll
      for (int j = 0; j < 8; ++j) {
        float v = G1[(size_t)(k0 + j) * 256];
        short a0 = bf16_rne(v);
        t0[j] = a0; t1[j] = bf16_rne(v - bf16f(a0));
        float v2 = G2[(size_t)(k0 + j) * 256];
        short d0 = bf16_rne(v2);
        u0[j] = d0; u1[j] = bf16_rne(v2 - bf16f(d0));
      }
      wg1a[ks] = t0; wg1b[ks] = t1; wg2a[ks] = u0; wg2b[ks] = u1;
    }
  }
  __syncthreads();

  int xr = tid & 15, xc = tid >> 4;   // xc 0..31
  int sr = tid >> 5, sc0 = (tid & 31) << 3;   // staging: 8 elems/thread

  auto ldx = [&](int tt, float& za, float& zb, float& g1x, float& ya, float& yb, float& g2x) {
    const float* base = g_X + (size_t)(tt * 64 + rb0 + xr) * 1536;
    float2 v1 = *(const float2*)(base + cg * 64 + 2 * xc);
    za = v1.x; zb = v1.y;
    g1x = base[512 + cg * 32 + xc];
    float2 v2 = *(const float2*)(base + 768 + cg * 64 + 2 * xc);
    ya = v2.x; yb = v2.y;
    g2x = base[1280 + cg * 32 + xc];
  };
  float cz1a = 0.f, cz1b = 0.f, cg1x = 0.f, cz2a = 0.f, cz2b = 0.f, cg2x = 0.f;
  if (L == 0) ldx(0, cz1a, cz1b, cg1x, cz2a, cz2b, cg2x);

#define GPOLL(PH, NEED)                                                        \
  {                                                                            \
    if (tid < 8) {                                                             \
      const unsigned long long* sp_ = &g_sent[L][dm][PH][tid];                 \
      while ((int)((unsigned)(ld64(sp_) >> 32) - (NEED)) < 0)                  \
        __builtin_amdgcn_s_sleep(2);                                           \
    }                                                                          \
    __syncthreads();                                                           \
  }

// speculative 8-wide load: declare cp_/v_ in the current scope
#define SPECLD8(CHIDX)                                                         \
  const unsigned long long* cp_ = &ch[CHIDX][sr * 256 + sc0];                  \
  unsigned long long v_[8];                                                    \
  _Pragma("unroll")                                                            \
  for (int i_ = 0; i_ < 8; ++i_) v_[i_] = ld64(cp_ + i_);

#define VERIFY8(EXP, DEPOSIT)                                                  \
  {                                                                            \
    unsigned pend_ = 0;                                                        \
    _Pragma("unroll")                                                          \
    for (int i_ = 0; i_ < 8; ++i_)                                             \
      if ((unsigned)(v_[i_] >> 32) != (EXP)) pend_ |= 1u << i_;                \
    while (pend_) {                                                            \
      __builtin_amdgcn_s_sleep(1);                                             \
      _Pragma("unroll")                                                        \
      for (int i_ = 0; i_ < 8; ++i_)                                           \
        if (pend_ & (1u << i_)) {                                              \
          v_[i_] = ld64(cp_ + i_);                                             \
          if ((unsigned)(v_[i_] >> 32) == (EXP)) pend_ &= ~(1u << i_);         \
        }                                                                      \
    }                                                                          \
    _Pragma("unroll")                                                          \
    for (int i_ = 0; i_ < 8; ++i_) { DEPOSIT; }                                \
  }

#define DEP_SPLIT(HARR)                                                        \
  { int hv2_ = (int)(unsigned)v_[i_];                                          \
    HARR[sr][sc0 + i_] = hv2_;                                                 \
    float fv_ = (float)hv2_;                                                   \
    short a0_ = bf16_rne(fv_); float r1_ = fv_ - bf16f(a0_);                   \
    short a1_ = bf16_rne(r1_); float r2_ = r1_ - bf16f(a1_);                   \
    phi[sr][sc0 + i_] = a0_; pmi[sr][sc0 + i_] = a1_;                          \
    plo[sr][sc0 + i_] = bf16_rne(r2_); }

#define SPLIT3(SRC)                                                            \
  {                                                                            \
    _Pragma("unroll")                                                          \
    for (int i_ = 0; i_ < 8; ++i_) {                                           \
      float v = (float)SRC[sr][sc0 + i_];                                      \
      short a0 = bf16_rne(v); float r1 = v - bf16f(a0);                        \
      short a1 = bf16_rne(r1); float r2 = r1 - bf16f(a1);                      \
      phi[sr][sc0 + i_] = a0; pmi[sr][sc0 + i_] = a1;                          \
      plo[sr][sc0 + i_] = bf16_rne(r2);                                        \
    }                                                                          \
  }

  for (int t = 0; t < 512; ++t) {
    unsigned tagp = (ep << 10) | (unsigned)(t + 1);

    float nz1a, nz1b, ng1x, nz2a, nz2b, ng2x;
    if (L == 0) {
      int tn = (t + 1 < 512) ? t + 1 : t;
      ldx(tn, nz1a, nz1b, ng1x, nz2a, nz2b, ng2x);   // prefetch next step's X0
    }

    // L1: batched speculative prefetch of this step's 6 x1 values
    const unsigned long long *xq0, *xq1, *xq2, *xq3, *xq4, *xq5;
    unsigned long long x0v = 0, x1v = 0, x2v = 0, x3v = 0, x4v = 0, x5v = 0;
    if (L == 1) {
      const unsigned long long* xb = &g_x1r[((size_t)((t & 31) * 64) + rb0 + xr) * 1536];
      xq0 = xb + cg * 64 + 2 * xc;        xq1 = xq0 + 1;
      xq2 = xb + 512 + cg * 32 + xc;
      xq3 = xb + 768 + cg * 64 + 2 * xc;  xq4 = xq3 + 1;
      xq5 = xb + 1280 + cg * 32 + xc;
      x0v = ld64(xq0); x1v = ld64(xq1); x2v = ld64(xq2);
      x3v = ld64(xq3); x4v = ld64(xq4); x5v = ld64(xq5);
    }

    // ================= P1: z1 =================
    if (t > 0) {
      SPECLD8(5)
      GPOLL(3, (ep << 10) | (unsigned)t)
      VERIFY8((ep << 10) | (unsigned)t, DEP_SPLIT(h2i))
    } else {
      SPLIT3(h2i);
    }
    __syncthreads();
    {
      int nt = wv & 3, kh = wv >> 2;
      floatx4 acc = {0.f, 0.f, 0.f, 0.f};
#pragma unroll
      for (int ks = 0; ks < 4; ++ks) {
        int k0 = kh * 128 + ks * 32 + lq * 8;
        short8 a0 = *(short8*)&phi[lm][k0];
        short8 a1 = *(short8*)&pmi[lm][k0];
        short8 a2 = *(short8*)&plo[lm][k0];
        acc = MFMA16(a0, wz1a[ks], acc);
        acc = MFMA16(a0, wz1b[ks], acc);
        acc = MFMA16(a1, wz1a[ks], acc);
        acc = MFMA16(a1, wz1b[ks], acc);
        acc = MFMA16(a0, wz1c[ks], acc);
        acc = MFMA16(a2, wz1a[ks], acc);
      }
#pragma unroll
      for (int i = 0; i < 4; ++i) redbuf[kh * 1088 + (lq * 4 + i) * 68 + nt * 16 + lm] = acc[i];
    }
    __syncthreads();
    // L1: verify x1 prefetch (tags almost always valid; retry is the backstop)
    if (L == 1) {
      unsigned xp = 0;
      if ((unsigned)(x0v >> 32) != tagp) xp |= 1u;
      if ((unsigned)(x1v >> 32) != tagp) xp |= 2u;
      if ((unsigned)(x2v >> 32) != tagp) xp |= 4u;
      if ((unsigned)(x3v >> 32) != tagp) xp |= 8u;
      if ((unsigned)(x4v >> 32) != tagp) xp |= 16u;
      if ((unsigned)(x5v >> 32) != tagp) xp |= 32u;
      while (xp) {
        __builtin_amdgcn_s_sleep(1);
        if (xp & 1u)  { x0v = ld64(xq0); if ((unsigned)(x0v >> 32) == tagp) xp &= ~1u; }
        if (xp & 2u)  { x1v = ld64(xq1); if ((unsigned)(x1v >> 32) == tagp) xp &= ~2u; }
        if (xp & 4u)  { x2v = ld64(xq2); if ((unsigned)(x2v >> 32) == tagp) xp &= ~4u; }
        if (xp & 8u)  { x3v = ld64(xq3); if ((unsigned)(x3v >> 32) == tagp) xp &= ~8u; }
        if (xp & 16u) { x4v = ld64(xq4); if ((unsigned)(x4v >> 32) == tagp) xp &= ~16u; }
        if (xp & 32u) { x5v = ld64(xq5); if ((unsigned)(x5v >> 32) == tagp) xp &= ~32u; }
      }
      cz1a = __uint_as_float((unsigned)x0v);
      cz1b = __uint_as_float((unsigned)x1v);
      cg1x = __uint_as_float((unsigned)x2v);
      cz2a = __uint_as_float((unsigned)x3v);
      cz2b = __uint_as_float((unsigned)x4v);
      cg2x = __uint_as_float((unsigned)x5v);
    }
    {
#pragma unroll
      for (int u = 0; u < 2; ++u) {
        int cc = 2 * xc + u;
        float pre = redbuf[xr * 68 + cc] + redbuf[1088 + xr * 68 + cc] + (u ? cz1b : cz1a);
        float s = 1.0f / (1.0f + expf(-pre));
        int gcol = cg * 64 + cc;
        if (gcol < 256) {
          float qf = floorf((0.875f * s + 0.125f) * 1024.0f);
          int qi = (int)qf; qi = qi < 1 ? 1 : (qi > 1024 ? 1024 : qi);
          st64(&ch[0][xr * 256 + gcol], ((unsigned long long)tagp << 32) | (unsigned)qi);
        } else {
          int rc = gcol - 256;
          float p = s * ((float)h2i[xr][rc] * INV_S);
          short p0 = bf16_rne(p);
          short p1s = bf16_rne(p - bf16f(p0));
          unsigned pay = ((unsigned)(unsigned short)p0 << 16) | (unsigned)(unsigned short)p1s;
          st64(&ch[1][xr * 256 + rc], ((unsigned long long)tagp << 32) | pay);
        }
      }
    }
    __syncthreads();   // drain P1 stores (compiler emits vmcnt(0) before barrier)
    if (tid == 0) st64(&g_sent[L][dm][0][cg], ((unsigned long long)tagp << 32) | 1u);

    // ================= P2: g1 + h1 update =================
    int qv;
    {
      SPECLD8(1)
      const unsigned long long* qp_ = &ch[0][xr * 256 + cg * 32 + xc];
      unsigned long long q64_ = ld64(qp_);
      GPOLL(0, tagp)
      VERIFY8(tagp, { unsigned pl_ = (unsigned)v_[i_];
                      phi[sr][sc0 + i_] = (short)(pl_ >> 16);
                      plo[sr][sc0 + i_] = (short)(pl_ & 0xFFFFu); })
      while ((unsigned)(q64_ >> 32) != tagp) {
        __builtin_amdgcn_s_sleep(1);
        q64_ = ld64(qp_);
      }
      qv = (int)(unsigned)q64_;
    }
    __syncthreads();
    {
      int ntg = wv & 1, kq = wv >> 1;
      floatx4 acc = {0.f, 0.f, 0.f, 0.f};
#pragma unroll
      for (int ks = 0; ks < 2; ++ks) {
        int k0 = kq * 64 + ks * 32 + lq * 8;
        short8 a0 = *(short8*)&phi[lm][k0];
        short8 a1 = *(short8*)&plo[lm][k0];
        acc = MFMA16(a0, wg1a[ks], acc);
        acc = MFMA16(a1, wg1a[ks], acc);
        acc = MFMA16(a0, wg1b[ks], acc);
      }
#pragma unroll
      for (int i = 0; i < 4; ++i) redbuf[kq * 576 + (lq * 4 + i) * 36 + ntg * 16 + lm] = acc[i];
    }
    __syncthreads();
    {
      float pre = redbuf[xr * 36 + xc] + redbuf[576 + xr * 36 + xc]
                + redbuf[1152 + xr * 36 + xc] + redbuf[1728 + xr * 36 + xc] + cg1x;
      float g = tanhf(pre);
      int gc = cg * 32 + xc;
      int q = qv;
      int hold = h1i[xr][gc];
      float zf = (float)q * (1.0f / 1024.0f);
      int ni = (int)rintf((1.0f - zf) * g * SCALE_F);
      int hnew = (hold >> 10) * q + (((hold & 1023) * q) >> 10) + ni;
      if (t >= lens[xr]) hnew = hold;
      st64(&ch[2][xr * 256 + gc], ((unsigned long long)tagp << 32) | (unsigned)hnew);
      if (L == 0)
        st64(&g_h0s[((size_t)(t * 64) + rb0 + xr) * 512 + gc],
             ((unsigned long long)tagp << 32) | __float_as_uint((float)hnew * INV_S));
      else if (gc < 100) d_out[65536 + (t + 1) * 6400 + (rb0 + xr) * 100 + gc] = hnew;
      if (t == 511) d_out[L * 32768 + (rb0 + xr) * 512 + gc] = hnew;
    }
    __syncthreads();   // protect h1i old-value reads before P3 staging overwrites
    if (tid == 0) st64(&g_sent[L][dm][1][cg], ((unsigned long long)tagp << 32) | 1u);

    // ================= P3: z2 =================
    {
      SPECLD8(2)
      GPOLL(1, tagp)
      VERIFY8(tagp, DEP_SPLIT(h1i))
    }
    __syncthreads();
    {
      int nt = wv & 3, kh = wv >> 2;
      floatx4 acc = {0.f, 0.f, 0.f, 0.f};
#pragma unroll
      for (int ks = 0; ks < 4; ++ks) {
        int k0 = kh * 128 + ks * 32 + lq * 8;
        short8 a0 = *(short8*)&phi[lm][k0];
        short8 a1 = *(short8*)&pmi[lm][k0];
        short8 a2 = *(short8*)&plo[lm][k0];
        acc = MFMA16(a0, wz2a[ks], acc);
        acc = MFMA16(a0, wz2b[ks], acc);
        acc = MFMA16(a1, wz2a[ks], acc);
        acc = MFMA16(a1, wz2b[ks], acc);
        acc = MFMA16(a0, wz2c[ks], acc);
        acc = MFMA16(a2, wz2a[ks], acc);
      }
#pragma unroll
      for (int i = 0; i < 4; ++i) redbuf[kh * 1088 + (lq * 4 + i) * 68 + nt * 16 + lm] = acc[i];
    }
    __syncthreads();
    {
#pragma unroll
      for (int u = 0; u < 2; ++u) {
        int cc = 2 * xc + u;
        float pre = redbuf[xr * 68 + cc] + redbuf[1088 + xr * 68 + cc] + (u ? cz2b : cz2a);
        float s = 1.0f / (1.0f + expf(-pre));
        int gcol = cg * 64 + cc;
        if (gcol < 256) {
          float qf = floorf((0.875f * s + 0.125f) * 1024.0f);
          int qi = (int)qf; qi = qi < 1 ? 1 : (qi > 1024 ? 1024 : qi);
          st64(&ch[3][xr * 256 + gcol], ((unsigned long long)tagp << 32) | (unsigned)qi);
        } else {
          int rc = gcol - 256;
          float p = s * ((float)h1i[xr][rc] * INV_S);
          short p0 = bf16_rne(p);
          short p1s = bf16_rne(p - bf16f(p0));
          unsigned pay = ((unsigned)(unsigned short)p0 << 16) | (unsigned)(unsigned short)p1s;
          st64(&ch[4][xr * 256 + rc], ((unsigned long long)tagp << 32) | pay);
        }
      }
    }
    __syncthreads();   // drain P3 stores
    if (tid == 0) st64(&g_sent[L][dm][2][cg], ((unsigned long long)tagp << 32) | 1u);

    // ================= P4: g2 + h2 update =================
    int qv2;
    {
      SPECLD8(4)
      const unsigned long long* qp_ = &ch[3][xr * 256 + cg * 32 + xc];
      unsigned long long q64_ = ld64(qp_);
      GPOLL(2, tagp)
      VERIFY8(tagp, { unsigned pl_ = (unsigned)v_[i_];
                      phi[sr][sc0 + i_] = (short)(pl_ >> 16);
                      plo[sr][sc0 + i_] = (short)(pl_ & 0xFFFFu); })
      while ((unsigned)(q64_ >> 32) != tagp) {
        __builtin_amdgcn_s_sleep(1);
        q64_ = ld64(qp_);
      }
      qv2 = (int)(unsigned)q64_;
    }
    __syncthreads();
    {
      int ntg = wv & 1, kq = wv >> 1;
      floatx4 acc = {0.f, 0.f, 0.f, 0.f};
#pragma unroll
      for (int ks = 0; ks < 2; ++ks) {
        int k0 = kq * 64 + ks * 32 + lq * 8;
        short8 a0 = *(short8*)&phi[lm][k0];
        short8 a1 = *(short8*)&plo[lm][k0];
        acc = MFMA16(a0, wg2a[ks], acc);
        acc = MFMA16(a1, wg2a[ks], acc);
        acc = MFMA16(a0, wg2b[ks], acc);
      }
#pragma unroll
      for (int i = 0; i < 4; ++i) redbuf[kq * 576 + (lq * 4 + i) * 36 + ntg * 16 + lm] = acc[i];
    }
    __syncthreads();
    {
      float pre = redbuf[xr * 36 + xc] + redbuf[576 + xr * 36 + xc]
                + redbuf[1152 + xr * 36 + xc] + redbuf[1728 + xr * 36 + xc] + cg2x;
      float g = tanhf(pre);
      int gc = cg * 32 + xc;
      int q = qv2;
      int hold = h2i[xr][gc];
      float zf = (float)q * (1.0f / 1024.0f);
      int ni = (int)rintf((1.0f - zf) * g * SCALE_F);
      int hnew = (hold >> 10) * q + (((hold & 1023) * q) >> 10) + ni;
      if (t >= lens[xr]) hnew = hold;
      st64(&ch[5][xr * 256 + gc], ((unsigned long long)tagp << 32) | (unsigned)hnew);
      if (L == 0)
        st64(&g_h0s[((size_t)(t * 64) + rb0 + xr) * 512 + 256 + gc],
             ((unsigned long long)tagp << 32) | __float_as_uint((float)hnew * INV_S));
      if (t == 511) d_out[L * 32768 + (rb0 + xr) * 512 + 256 + gc] = hnew;
    }
    __syncthreads();   // protect h2i old-value reads before next-step P1 staging
    if (tid == 0) st64(&g_sent[L][dm][3][cg], ((unsigned long long)tagp << 32) | 1u);

    if (L == 0) {
      cz1a = nz1a; cz1b = nz1b; cg1x = ng1x; cz2a = nz2a; cz2b = nz2b; cg2x = ng2x;
    }
  }
#undef GPOLL
#undef SPECLD8
#undef VERIFY8
#undef DEP_SPLIT
#undef SPLIT3
}

// ------------------------------------------------------------------
extern "C" void kernel_launch(void* const* d_in, const int* in_sizes, int n_in,
                              void* d_out, int out_size, void* d_ws, size_t ws_size,
                              hipStream_t stream) {
  const int*   seq     = (const int*)d_in[0];
  const int*   lengths = (const int*)d_in[1];
  const float* emb     = (const float*)d_in[2];
  const float* Wz1     = (const float*)d_in[3];
  const float* bz1     = (const float*)d_in[4];
  const float* Wg1     = (const float*)d_in[5];
  const float* bg1     = (const float*)d_in[6];
  const float* Wz2     = (const float*)d_in[7];
  const float* bz2     = (const float*)d_in[8];
  const float* Wg2     = (const float*)d_in[9];
  const float* bg2     = (const float*)d_in[10];
  int* out = (int*)d_out;
  (void)in_sizes; (void)n_in; (void)out_size; (void)d_ws; (void)ws_size;

  bump_epoch<<<1, 1, 0, stream>>>();
  prep_x<<<3072, 256, 0, stream>>>(Wz1, bz1, Wg1, bg1, Wz2, bz2, Wg2, bg2, 0, out, 1);
  prep_x<<<3072, 256, 0, stream>>>(Wz1, bz1, Wg1, bg1, Wz2, bz2, Wg2, bg2, 1, out, 0);
  gemmx_kernel<<<dim3(256, 12), 256, 0, stream>>>(seq, emb);
  fused_kernel<<<112, 512, 0, stream>>>(Wz1, Wg1, Wz2, Wg2, lengths, out);
}

// Round 4
// 8531.898 us; speedup vs baseline: 1.4079x; 1.4079x over previous
//
#include <hip/hip_runtime.h>
#include <stdint.h>

// RevGRU encoder, MI355X.
// R10: revert R9's harmful scan-phase speculation (lockstep producers -> spec
// loads mostly stale -> 2x read traffic at the coherent point during rendezvous;
// 8.74 -> 12.0ms). Back to the R8 structure (4-hop + sentinel gates + XCD
// colocation, 8.74ms) with two surviving deltas:
//  (1) L1 x1-ring reads: issue all 6 loads at step top (producers run up to 24
//      steps ahead of L1, tags genuinely valid), verify at the ORIGINAL R8 use
//      points. Issue-early/consume-same-place dominates R8; miss fallback is
//      exactly R8's rdx poll.
//  (2) sentinel poll sleep 2 -> 1 (8 threads polling; negligible traffic,
//      ~50ns faster detection per hop). launch_bounds (512,1): 112 WGs on
//      256 CUs = 1 WG/CU regardless; don't cap VGPRs at 128.

typedef __attribute__((ext_vector_type(8))) short short8;
typedef __attribute__((ext_vector_type(4))) float floatx4;

#define MFMA16(a,b,c) __builtin_amdgcn_mfma_f32_16x16x32_bf16((a),(b),(c),0,0,0)

__device__ __forceinline__ short bf16_rne(float f) {
  uint32_t u = __float_as_uint(f);
  u += 0x7FFFu + ((u >> 16) & 1u);
  return (short)(u >> 16);
}
__device__ __forceinline__ float bf16f(short s) {
  return __uint_as_float(((uint32_t)(uint16_t)s) << 16);
}
__device__ __forceinline__ void st64(unsigned long long* p, unsigned long long v) {
  __hip_atomic_store(p, v, __ATOMIC_RELAXED, __HIP_MEMORY_SCOPE_AGENT);
}
__device__ __forceinline__ unsigned long long ld64(const unsigned long long* p) {
  return __hip_atomic_load(p, __ATOMIC_RELAXED, __HIP_MEMORY_SCOPE_AGENT);
}

#define SCALE_F 8388608.0f
#define INV_S   (1.0f/8388608.0f)

// ---- static device scratch ----
__device__ float g_X[50331648];            // X0: 32768 x 1536 (layer-0 x-projections)
__device__ short g_WTh[2][786432];         // per-layer x-proj weights, transposed, split hi
__device__ short g_WTl[2][786432];         // split lo
__device__ float g_biasL[2][1536];
__device__ unsigned long long g_ch[2][4][6][4096];  // per-layer scan channels
__device__ unsigned long long g_h0s[16777216];      // [t][row][col] tagged {tag, f32 h0f}
__device__ unsigned long long g_x1r[3145728];       // ring [t&31][row][1536] tagged {tag, f32}
__device__ unsigned long long g_sent[2][4][4][8];   // sentinels [L][dm][phase][cg]
__device__ unsigned g_epoch;

__global__ void bump_epoch() { g_epoch = g_epoch + 1u; }

// ------------------------------------------------------------------
__global__ void prep_x(const float* __restrict__ Wz1, const float* __restrict__ bz1,
                       const float* __restrict__ Wg1, const float* __restrict__ bg1,
                       const float* __restrict__ Wz2, const float* __restrict__ bz2,
                       const float* __restrict__ Wg2, const float* __restrict__ bg2,
                       int layer, int* __restrict__ d_out, int zero_extra) {
  int idx = blockIdx.x * 256 + threadIdx.x;   // grid covers 512*1536 exactly
  int k = idx / 1536;
  int c = idx - k * 1536;
  const float* W; const float* bb; int cc; int ncols;
  if (c < 512)       { W = Wz1; bb = bz1; cc = c;        ncols = 512; }
  else if (c < 768)  { W = Wg1; bb = bg1; cc = c - 512;  ncols = 256; }
  else if (c < 1280) { W = Wz2; bb = bz2; cc = c - 768;  ncols = 512; }
  else               { W = Wg2; bb = bg2; cc = c - 1280; ncols = 256; }
  float wv = W[(size_t)layer * 768 * ncols + (size_t)k * ncols + cc];
  short hi = bf16_rne(wv);
  short lo = bf16_rne(wv - bf16f(hi));
  g_WTh[layer][(size_t)c * 512 + k] = hi;
  g_WTl[layer][(size_t)c * 512 + k] = lo;
  if (k == 0) g_biasL[layer][c] = bb[layer * ncols + cc];
  if (zero_extra && idx < 6400) d_out[65536 + idx] = 0;   // saved[0] = h0 = zeros
}

// ------------------------------------------------------------------
__global__ __launch_bounds__(256)
void gemmx_kernel(const int* __restrict__ seq, const float* __restrict__ emb) {
  __shared__ float At[128][36];
  __shared__ short Bhi[128][40];
  __shared__ short Blo[128][40];
  __shared__ int toks[128];
  int tid = threadIdx.x;
  int r0 = blockIdx.x * 128;
  int c0 = blockIdx.y * 128;
  if (tid < 128) toks[tid] = seq[r0 + tid];
  int lane = tid & 63;
  int wid = tid >> 6;
  int wm = wid & 1, wn = wid >> 1;
  int lm = lane & 15, lq = lane >> 4;
  floatx4 zero4 = {0.f, 0.f, 0.f, 0.f};
  floatx4 acc[4][4];
#pragma unroll
  for (int a = 0; a < 4; ++a)
#pragma unroll
    for (int b = 0; b < 4; ++b) acc[a][b] = zero4;
  __syncthreads();
  int am = tid >> 1;
  int ah = (tid & 1) * 16;
  const float* arow = emb + (size_t)toks[am] * 512;
  const short* bh_base = g_WTh[0] + (size_t)(c0 + am) * 512;
  const short* bl_base = g_WTl[0] + (size_t)(c0 + am) * 512;
  for (int kb = 0; kb < 16; ++kb) {
    int k0 = kb * 32 + ah;
    float4 a0 = *(const float4*)(arow + k0);
    float4 a1 = *(const float4*)(arow + k0 + 4);
    float4 a2 = *(const float4*)(arow + k0 + 8);
    float4 a3 = *(const float4*)(arow + k0 + 12);
    short4 b0 = *(const short4*)(bh_base + k0);
    short4 b1 = *(const short4*)(bh_base + k0 + 4);
    short4 b2 = *(const short4*)(bh_base + k0 + 8);
    short4 b3 = *(const short4*)(bh_base + k0 + 12);
    short4 l0 = *(const short4*)(bl_base + k0);
    short4 l1 = *(const short4*)(bl_base + k0 + 4);
    short4 l2 = *(const short4*)(bl_base + k0 + 8);
    short4 l3 = *(const short4*)(bl_base + k0 + 12);
    __syncthreads();
    *(float4*)&At[am][ah]      = a0;
    *(float4*)&At[am][ah + 4]  = a1;
    *(float4*)&At[am][ah + 8]  = a2;
    *(float4*)&At[am][ah + 12] = a3;
    *(short4*)&Bhi[am][ah]      = b0;
    *(short4*)&Bhi[am][ah + 4]  = b1;
    *(short4*)&Bhi[am][ah + 8]  = b2;
    *(short4*)&Bhi[am][ah + 12] = b3;
    *(short4*)&Blo[am][ah]      = l0;
    *(short4*)&Blo[am][ah + 4]  = l1;
    *(short4*)&Blo[am][ah + 8]  = l2;
    *(short4*)&Blo[am][ah + 12] = l3;
    __syncthreads();
    short8 afh[4], afl[4];
#pragma unroll
    for (int mt = 0; mt < 4; ++mt) {
      const float* ap = &At[wm*64 + mt*16 + lm][lq*8];
#pragma unroll
      for (int j = 0; j < 8; ++j) {
        float v = ap[j];
        short hi = bf16_rne(v);
        afh[mt][j] = hi;
        afl[mt][j] = bf16_rne(v - bf16f(hi));
      }
    }
#pragma unroll
    for (int nt = 0; nt < 4; ++nt) {
      short8 bfh = *(short8*)&Bhi[wn*64 + nt*16 + lm][lq*8];
      short8 bfl = *(short8*)&Blo[wn*64 + nt*16 + lm][lq*8];
#pragma unroll
      for (int mt = 0; mt < 4; ++mt) {
        acc[mt][nt] = MFMA16(afh[mt], bfh, acc[mt][nt]);
        acc[mt][nt] = MFMA16(afl[mt], bfh, acc[mt][nt]);
        acc[mt][nt] = MFMA16(afh[mt], bfl, acc[mt][nt]);
      }
    }
  }
#pragma unroll
  for (int nt = 0; nt < 4; ++nt) {
    int gc = c0 + wn*64 + nt*16 + lm;
    float bv = g_biasL[0][gc];
#pragma unroll
    for (int mt = 0; mt < 4; ++mt) {
#pragma unroll
      for (int i = 0; i < 4; ++i) {
        int gr = r0 + wm*64 + mt*16 + lq*4 + i;
        g_X[(size_t)gr * 1536 + gc] = acc[mt][nt][i] + bv;
      }
    }
  }
}

// ------------------------------------------------------------------
__global__ __launch_bounds__(512, 1)
void fused_kernel(const float* __restrict__ Wz1g, const float* __restrict__ Wg1g,
                  const float* __restrict__ Wz2g, const float* __restrict__ Wg2g,
                  const int* __restrict__ lengths, int* __restrict__ d_out) {
  __shared__ int   h1i[16][260];
  __shared__ int   h2i[16][260];
  __shared__ short phi[16][264];
  __shared__ short pmi[16][264];
  __shared__ short plo[16][264];
  __shared__ float redbuf[2304];
  __shared__ int lens[16];
  __shared__ short ahs[16][520];
  __shared__ short als[16][520];

  int tid = threadIdx.x;
  int bid = blockIdx.x;
  int lane = tid & 63, wv = tid >> 6;   // 8 waves
  int lm = lane & 15, lq = lane >> 4;
  unsigned ep = g_epoch;

  if (bid >= 64) {
    // ================== role: X1 producer (48 WGs) ==================
    int xw = bid - 64;
    int r4 = xw & 3;        // row tile (16 rows) == dm of the L0 group it consumes
    int cs = xw >> 2;       // col slice (128 cols), 0..11
    int colx = cs * 128 + wv * 16 + lm;     // this lane's output column
    short8 bh[16], bl[16];
#pragma unroll
    for (int kf = 0; kf < 16; ++kf) {
      bh[kf] = *(const short8*)&g_WTh[1][(size_t)colx * 512 + kf * 32 + lq * 8];
      bl[kf] = *(const short8*)&g_WTl[1][(size_t)colx * 512 + kf * 32 + lq * 8];
    }
    float bvx = g_biasL[1][colx];
    int sr2 = tid >> 5;             // row 0..15
    int cb  = (tid & 31) * 16;      // 16 cols each

    for (int t = 0; t < 512; ++t) {
      unsigned tagt = (ep << 10) | (unsigned)(t + 1);
      // gate: wait until all 8 L0 WGs of domain r4 finished step t's P4
      if (tid < 8) {
        const unsigned long long* sp = &g_sent[0][r4][3][tid];
        while ((int)((unsigned)(ld64(sp) >> 32) - tagt) < 0) __builtin_amdgcn_s_sleep(1);
      }
      __syncthreads();
      // stage h0s[t] rows r4*16..+16 (one-shot after gate; verify loop = backstop)
      {
        const unsigned long long* hp = &g_h0s[((size_t)(t * 64) + r4 * 16 + sr2) * 512 + cb];
        unsigned long long v[16];
        do { v[0] = ld64(hp); } while ((unsigned)(v[0] >> 32) != tagt);
#pragma unroll
        for (int i = 1; i < 16; ++i) v[i] = ld64(hp + i);
        unsigned pend = 0;
#pragma unroll
        for (int i = 1; i < 16; ++i)
          if ((unsigned)(v[i] >> 32) != tagt) pend |= 1u << i;
        while (pend) {
          __builtin_amdgcn_s_sleep(1);
#pragma unroll
          for (int i = 1; i < 16; ++i)
            if (pend & (1u << i)) {
              v[i] = ld64(hp + i);
              if ((unsigned)(v[i] >> 32) == tagt) pend &= ~(1u << i);
            }
        }
#pragma unroll
        for (int i = 0; i < 16; ++i) {
          float f = __uint_as_float((unsigned)v[i]);
          short hi = bf16_rne(f);
          ahs[sr2][cb + i] = hi;
          als[sr2][cb + i] = bf16_rne(f - bf16f(hi));
        }
      }
      __syncthreads();
      floatx4 acc = {0.f, 0.f, 0.f, 0.f};
#pragma unroll
      for (int kf = 0; kf < 16; ++kf) {
        short8 a0 = *(short8*)&ahs[lm][kf * 32 + lq * 8];
        short8 a1 = *(short8*)&als[lm][kf * 32 + lq * 8];
        acc = MFMA16(a0, bh[kf], acc);
        acc = MFMA16(a1, bh[kf], acc);
        acc = MFMA16(a0, bl[kf], acc);
      }
      // throttle: don't clobber ring slots L1 hasn't consumed (window 24 of 32)
      if (t >= 25) {
        if (tid < 4) {
          unsigned need = (ep << 10) | (unsigned)(t - 24);
          while ((unsigned)(ld64(&g_ch[1][tid][5][0]) >> 32) < need) __builtin_amdgcn_s_sleep(2);
        }
      }
      __syncthreads();
#pragma unroll
      for (int i = 0; i < 4; ++i) {
        int row = r4 * 16 + lq * 4 + i;
        st64(&g_x1r[((size_t)(t & 31) * 64 + row) * 1536 + colx],
             ((unsigned long long)tagt << 32) | __float_as_uint(acc[i] + bvx));
      }
      __syncthreads();   // before next stage overwrites ahs/als
    }
    return;
  }

  // ================== role: scan (layer L), 32 WGs each ==================
  // XCD colocation: the 8 cooperating WGs of a (L,dm) group share bid%8.
  int grp = bid & 7;
  int cg  = bid >> 3;     // column group 0..7
  int L   = grp >> 2;
  int dm  = grp & 3;      // batch domain 0..3
  int rb0 = dm * 16;
  unsigned long long (*ch)[4096] = g_ch[L][dm];

  if (tid < 16) lens[tid] = lengths[rb0 + tid];
  for (int i = tid; i < 16 * 260; i += 512) { ((int*)h1i)[i] = 0; ((int*)h2i)[i] = 0; }

  // ---- preload recurrent-weight B-frags into registers (split-bf16) ----
  short8 wz1a[4], wz1b[4], wz1c[4], wz2a[4], wz2b[4], wz2c[4];
  short8 wg1a[2], wg1b[2], wg2a[2], wg2b[2];
  {
    int nt = wv & 3, kh = wv >> 2;
    int colz = cg * 64 + nt * 16 + lm;
    const float* W1 = Wz1g + (size_t)L * 768 * 512 + (size_t)512 * 512 + colz;
    const float* W2 = Wz2g + (size_t)L * 768 * 512 + (size_t)512 * 512 + colz;
#pragma unroll
    for (int ks = 0; ks < 4; ++ks) {
      int k0 = kh * 128 + ks * 32 + lq * 8;
      short8 t0, t1, t2, u0, u1, u2;
#pragma unroll
      for (int j = 0; j < 8; ++j) {
        float v = W1[(size_t)(k0 + j) * 512] * INV_S;   // pre-scale: A is raw int h
        short a0 = bf16_rne(v); float r1 = v - bf16f(a0);
        short a1 = bf16_rne(r1); float r2 = r1 - bf16f(a1);
        t0[j] = a0; t1[j] = a1; t2[j] = bf16_rne(r2);
        float v2 = W2[(size_t)(k0 + j) * 512] * INV_S;
        short d0 = bf16_rne(v2); float s1 = v2 - bf16f(d0);
        short d1 = bf16_rne(s1); float s2 = s1 - bf16f(d1);
        u0[j] = d0; u1[j] = d1; u2[j] = bf16_rne(s2);
      }
      wz1a[ks] = t0; wz1b[ks] = t1; wz1c[ks] = t2;
      wz2a[ks] = u0; wz2b[ks] = u1; wz2c[ks] = u2;
    }
    int ntg = wv & 1, kq = wv >> 1;
    int colg = cg * 32 + ntg * 16 + lm;
    const float* G1 = Wg1g + (size_t)L * 768 * 256 + (size_t)512 * 256 + colg;
    const float* G2 = Wg2g + (size_t)L * 768 * 256 + (size_t)512 * 256 + colg;
#pragma unroll
    for (int ks = 0; ks < 2; ++ks) {
      int k0 = kq * 64 + ks * 32 + lq * 8;
      short8 t0, t1, u0, u1;
#pragma unroll
      for (int j = 0; j < 8; ++j) {
        float v = G1[(size_t)(k0 + j) * 256];
        short a0 = bf16_rne(v);
        t0[j] = a0; t1[j] = bf16_rne(v - bf16f(a0));
        float v2 = G2[(size_t)(k0 + j) * 256];
        short d0 = bf16_rne(v2);
        u0[j] = d0; u1[j] = bf16_rne(v2 - bf16f(d0));
      }
      wg1a[ks] = t0; wg1b[ks] = t1; wg2a[ks] = u0; wg2b[ks] = u1;
    }
  }
  __syncthreads();

  int xr = tid & 15, xc = tid >> 4;   // xc 0..31
  int sr = tid >> 5, sc0 = (tid & 31) << 3;   // staging: 8 elems/thread

  // x1-ring column offsets (loop-invariant)
  int xo0 = cg * 64 + 2 * xc;          // z1 pair
  int xo1 = 512 + cg * 32 + xc;        // g1
  int xo2 = 768 + cg * 64 + 2 * xc;    // z2 pair
  int xo3 = 1280 + cg * 32 + xc;       // g2

  auto ldx = [&](int tt, float& za, float& zb, float& g1x, float& ya, float& yb, float& g2x) {
    const float* base = g_X + (size_t)(tt * 64 + rb0 + xr) * 1536;
    float2 v1 = *(const float2*)(base + cg * 64 + 2 * xc);
    za = v1.x; zb = v1.y;
    g1x = base[512 + cg * 32 + xc];
    float2 v2 = *(const float2*)(base + 768 + cg * 64 + 2 * xc);
    ya = v2.x; yb = v2.y;
    g2x = base[1280 + cg * 32 + xc];
  };
  float cz1a = 0.f, cz1b = 0.f, cg1x = 0.f, cz2a = 0.f, cz2b = 0.f, cg2x = 0.f;
  if (L == 0) ldx(0, cz1a, cz1b, cg1x, cz2a, cz2b, cg2x);

#define GATE(PH, NEED)                                                         \
  {                                                                            \
    if (tid < 8) {                                                             \
      const unsigned long long* sp_ = &g_sent[L][dm][PH][tid];                 \
      while ((int)((unsigned)(ld64(sp_) >> 32) - (NEED)) < 0)                  \
        __builtin_amdgcn_s_sleep(1);                                           \
    }                                                                          \
    __syncthreads();                                                           \
  }

#define STAGE8(CHIDX, EXP, DEPOSIT)                                            \
  {                                                                            \
    const unsigned long long* cp_ = &ch[CHIDX][sr * 256 + sc0];                \
    unsigned long long v_[8];                                                  \
    do { v_[0] = ld64(cp_); } while ((unsigned)(v_[0] >> 32) != (EXP));        \
    _Pragma("unroll")                                                          \
    for (int i_ = 1; i_ < 8; ++i_) v_[i_] = ld64(cp_ + i_);                    \
    unsigned pend_ = 0;                                                        \
    _Pragma("unroll")                                                          \
    for (int i_ = 1; i_ < 8; ++i_)                                             \
      if ((unsigned)(v_[i_] >> 32) != (EXP)) pend_ |= 1u << i_;                \
    while (pend_) {                                                            \
      __builtin_amdgcn_s_sleep(1);                                             \
      _Pragma("unroll")                                                        \
      for (int i_ = 1; i_ < 8; ++i_)                                           \
        if (pend_ & (1u << i_)) {                                              \
          v_[i_] = ld64(cp_ + i_);                                             \
          if ((unsigned)(v_[i_] >> 32) == (EXP)) pend_ &= ~(1u << i_);         \
        }                                                                      \
    }                                                                          \
    _Pragma("unroll")                                                          \
    for (int i_ = 0; i_ < 8; ++i_) { DEPOSIT; }                                \
  }

#define SPLIT3(SRC)                                                            \
  {                                                                            \
    _Pragma("unroll")                                                          \
    for (int i_ = 0; i_ < 8; ++i_) {                                           \
      float v = (float)SRC[sr][sc0 + i_];                                      \
      short a0 = bf16_rne(v); float r1 = v - bf16f(a0);                        \
      short a1 = bf16_rne(r1); float r2 = r1 - bf16f(a1);                      \
      phi[sr][sc0 + i_] = a0; pmi[sr][sc0 + i_] = a1;                          \
      plo[sr][sc0 + i_] = bf16_rne(r2);                                        \
    }                                                                          \
  }

  for (int t = 0; t < 512; ++t) {
    unsigned tagp = (ep << 10) | (unsigned)(t + 1);

    float nz1a, nz1b, ng1x, nz2a, nz2b, ng2x;
    if (L == 0) {
      int tn = (t + 1 < 512) ? t + 1 : t;
      ldx(tn, nz1a, nz1b, ng1x, nz2a, nz2b, ng2x);   // prefetch next step's X0
    }

    // L1: issue this step's 6 x1-ring loads early (producers run ahead; tags
    // usually already valid). Verified at the original use points below.
    const unsigned long long* xb = nullptr;
    unsigned long long x0v = 0, x1v = 0, x2v = 0, x3v = 0, x4v = 0, x5v = 0;
    if (L == 1) {
      xb = &g_x1r[((size_t)((t & 31) * 64) + rb0 + xr) * 1536];
      x0v = ld64(xb + xo0); x1v = ld64(xb + xo0 + 1);
      x2v = ld64(xb + xo1);
      x3v = ld64(xb + xo2); x4v = ld64(xb + xo2 + 1);
      x5v = ld64(xb + xo3);
    }
    auto vfy = [&](unsigned long long v, const unsigned long long* p) -> float {
      while ((unsigned)(v >> 32) != tagp) { __builtin_amdgcn_s_sleep(1); v = ld64(p); }
      return __uint_as_float((unsigned)v);
    };

    // ================= P1: z1 =================
    if (t > 0) {
      GATE(3, (ep << 10) | (unsigned)t);
      STAGE8(5, (ep << 10) | (unsigned)t, h2i[sr][sc0 + i_] = (int)(unsigned)v_[i_]);
    }
    SPLIT3(h2i);
    __syncthreads();
    {
      int nt = wv & 3, kh = wv >> 2;
      floatx4 acc = {0.f, 0.f, 0.f, 0.f};
#pragma unroll
      for (int ks = 0; ks < 4; ++ks) {
        int k0 = kh * 128 + ks * 32 + lq * 8;
        short8 a0 = *(short8*)&phi[lm][k0];
        short8 a1 = *(short8*)&pmi[lm][k0];
        short8 a2 = *(short8*)&plo[lm][k0];
        acc = MFMA16(a0, wz1a[ks], acc);
        acc = MFMA16(a0, wz1b[ks], acc);
        acc = MFMA16(a1, wz1a[ks], acc);
        acc = MFMA16(a1, wz1b[ks], acc);
        acc = MFMA16(a0, wz1c[ks], acc);
        acc = MFMA16(a2, wz1a[ks], acc);
      }
#pragma unroll
      for (int i = 0; i < 4; ++i) redbuf[kh * 1088 + (lq * 4 + i) * 68 + nt * 16 + lm] = acc[i];
    }
    __syncthreads();
    {
      if (L == 1) { cz1a = vfy(x0v, xb + xo0); cz1b = vfy(x1v, xb + xo0 + 1); }
#pragma unroll
      for (int u = 0; u < 2; ++u) {
        int cc = 2 * xc + u;
        float pre = redbuf[xr * 68 + cc] + redbuf[1088 + xr * 68 + cc] + (u ? cz1b : cz1a);
        float s = 1.0f / (1.0f + expf(-pre));
        int gcol = cg * 64 + cc;
        if (gcol < 256) {
          float qf = floorf((0.875f * s + 0.125f) * 1024.0f);
          int qi = (int)qf; qi = qi < 1 ? 1 : (qi > 1024 ? 1024 : qi);
          st64(&ch[0][xr * 256 + gcol], ((unsigned long long)tagp << 32) | (unsigned)qi);
        } else {
          int rc = gcol - 256;
          float p = s * ((float)h2i[xr][rc] * INV_S);
          short p0 = bf16_rne(p);
          short p1s = bf16_rne(p - bf16f(p0));
          unsigned pay = ((unsigned)(unsigned short)p0 << 16) | (unsigned)(unsigned short)p1s;
          st64(&ch[1][xr * 256 + rc], ((unsigned long long)tagp << 32) | pay);
        }
      }
    }
    __syncthreads();   // drain P1 stores (compiler emits vmcnt(0) before barrier)
    if (tid == 0) st64(&g_sent[L][dm][0][cg], ((unsigned long long)tagp << 32) | 1u);
    GATE(0, tagp);

    // ================= P2: g1 + h1 update =================
    int qv;
    STAGE8(1, tagp, { unsigned pl_ = (unsigned)v_[i_];
                      phi[sr][sc0 + i_] = (short)(pl_ >> 16);
                      plo[sr][sc0 + i_] = (short)(pl_ & 0xFFFFu); });
    {
      const unsigned long long* qp = &ch[0][xr * 256 + cg * 32 + xc];
      unsigned long long q64;
      do { q64 = ld64(qp); } while ((unsigned)(q64 >> 32) != tagp);
      qv = (int)(unsigned)q64;
    }
    __syncthreads();
    {
      int ntg = wv & 1, kq = wv >> 1;
      floatx4 acc = {0.f, 0.f, 0.f, 0.f};
#pragma unroll
      for (int ks = 0; ks < 2; ++ks) {
        int k0 = kq * 64 + ks * 32 + lq * 8;
        short8 a0 = *(short8*)&phi[lm][k0];
        short8 a1 = *(short8*)&plo[lm][k0];
        acc = MFMA16(a0, wg1a[ks], acc);
        acc = MFMA16(a1, wg1a[ks], acc);
        acc = MFMA16(a0, wg1b[ks], acc);
      }
#pragma unroll
      for (int i = 0; i < 4; ++i) redbuf[kq * 576 + (lq * 4 + i) * 36 + ntg * 16 + lm] = acc[i];
    }
    __syncthreads();
    {
      if (L == 1) cg1x = vfy(x2v, xb + xo1);
      float pre = redbuf[xr * 36 + xc] + redbuf[576 + xr * 36 + xc]
                + redbuf[1152 + xr * 36 + xc] + redbuf[1728 + xr * 36 + xc] + cg1x;
      float g = tanhf(pre);
      int gc = cg * 32 + xc;
      int q = qv;
      int hold = h1i[xr][gc];
      float zf = (float)q * (1.0f / 1024.0f);
      int ni = (int)rintf((1.0f - zf) * g * SCALE_F);
      int hnew = (hold >> 10) * q + (((hold & 1023) * q) >> 10) + ni;
      if (t >= lens[xr]) hnew = hold;
      st64(&ch[2][xr * 256 + gc], ((unsigned long long)tagp << 32) | (unsigned)hnew);
      if (L == 0)
        st64(&g_h0s[((size_t)(t * 64) + rb0 + xr) * 512 + gc],
             ((unsigned long long)tagp << 32) | __float_as_uint((float)hnew * INV_S));
      else if (gc < 100) d_out[65536 + (t + 1) * 6400 + (rb0 + xr) * 100 + gc] = hnew;
      if (t == 511) d_out[L * 32768 + (rb0 + xr) * 512 + gc] = hnew;
    }
    __syncthreads();   // protect h1i old-value reads before P3 staging overwrites
    if (tid == 0) st64(&g_sent[L][dm][1][cg], ((unsigned long long)tagp << 32) | 1u);
    GATE(1, tagp);

    // ================= P3: z2 =================
    STAGE8(2, tagp, h1i[sr][sc0 + i_] = (int)(unsigned)v_[i_]);
    SPLIT3(h1i);
    __syncthreads();
    {
      int nt = wv & 3, kh = wv >> 2;
      floatx4 acc = {0.f, 0.f, 0.f, 0.f};
#pragma unroll
      for (int ks = 0; ks < 4; ++ks) {
        int k0 = kh * 128 + ks * 32 + lq * 8;
        short8 a0 = *(short8*)&phi[lm][k0];
        short8 a1 = *(short8*)&pmi[lm][k0];
        short8 a2 = *(short8*)&plo[lm][k0];
        acc = MFMA16(a0, wz2a[ks], acc);
        acc = MFMA16(a0, wz2b[ks], acc);
        acc = MFMA16(a1, wz2a[ks], acc);
        acc = MFMA16(a1, wz2b[ks], acc);
        acc = MFMA16(a0, wz2c[ks], acc);
        acc = MFMA16(a2, wz2a[ks], acc);
      }
#pragma unroll
      for (int i = 0; i < 4; ++i) redbuf[kh * 1088 + (lq * 4 + i) * 68 + nt * 16 + lm] = acc[i];
    }
    __syncthreads();
    {
      if (L == 1) { cz2a = vfy(x3v, xb + xo2); cz2b = vfy(x4v, xb + xo2 + 1); }
#pragma unroll
      for (int u = 0; u < 2; ++u) {
        int cc = 2 * xc + u;
        float pre = redbuf[xr * 68 + cc] + redbuf[1088 + xr * 68 + cc] + (u ? cz2b : cz2a);
        float s = 1.0f / (1.0f + expf(-pre));
        int gcol = cg * 64 + cc;
        if (gcol < 256) {
          float qf = floorf((0.875f * s + 0.125f) * 1024.0f);
          int qi = (int)qf; qi = qi < 1 ? 1 : (qi > 1024 ? 1024 : qi);
          st64(&ch[3][xr * 256 + gcol], ((unsigned long long)tagp << 32) | (unsigned)qi);
        } else {
          int rc = gcol - 256;
          float p = s * ((float)h1i[xr][rc] * INV_S);
          short p0 = bf16_rne(p);
          short p1s = bf16_rne(p - bf16f(p0));
          unsigned pay = ((unsigned)(unsigned short)p0 << 16) | (unsigned)(unsigned short)p1s;
          st64(&ch[4][xr * 256 + rc], ((unsigned long long)tagp << 32) | pay);
        }
      }
    }
    __syncthreads();   // drain P3 stores
    if (tid == 0) st64(&g_sent[L][dm][2][cg], ((unsigned long long)tagp << 32) | 1u);
    GATE(2, tagp);

    // ================= P4: g2 + h2 update =================
    int qv2;
    STAGE8(4, tagp, { unsigned pl_ = (unsigned)v_[i_];
                      phi[sr][sc0 + i_] = (short)(pl_ >> 16);
                      plo[sr][sc0 + i_] = (short)(pl_ & 0xFFFFu); });
    {
      const unsigned long long* qp = &ch[3][xr * 256 + cg * 32 + xc];
      unsigned long long q64;
      do { q64 = ld64(qp); } while ((unsigned)(q64 >> 32) != tagp);
      qv2 = (int)(unsigned)q64;
    }
    __syncthreads();
    {
      int ntg = wv & 1, kq = wv >> 1;
      floatx4 acc = {0.f, 0.f, 0.f, 0.f};
#pragma unroll
      for (int ks = 0; ks < 2; ++ks) {
        int k0 = kq * 64 + ks * 32 + lq * 8;
        short8 a0 = *(short8*)&phi[lm][k0];
        short8 a1 = *(short8*)&plo[lm][k0];
        acc = MFMA16(a0, wg2a[ks], acc);
        acc = MFMA16(a1, wg2a[ks], acc);
        acc = MFMA16(a0, wg2b[ks], acc);
      }
#pragma unroll
      for (int i = 0; i < 4; ++i) redbuf[kq * 576 + (lq * 4 + i) * 36 + ntg * 16 + lm] = acc[i];
    }
    __syncthreads();
    {
      if (L == 1) cg2x = vfy(x5v, xb + xo3);
      float pre = redbuf[xr * 36 + xc] + redbuf[576 + xr * 36 + xc]
                + redbuf[1152 + xr * 36 + xc] + redbuf[1728 + xr * 36 + xc] + cg2x;
      float g = tanhf(pre);
      int gc = cg * 32 + xc;
      int q = qv2;
      int hold = h2i[xr][gc];
      float zf = (float)q * (1.0f / 1024.0f);
      int ni = (int)rintf((1.0f - zf) * g * SCALE_F);
      int hnew = (hold >> 10) * q + (((hold & 1023) * q) >> 10) + ni;
      if (t >= lens[xr]) hnew = hold;
      st64(&ch[5][xr * 256 + gc], ((unsigned long long)tagp << 32) | (unsigned)hnew);
      if (L == 0)
        st64(&g_h0s[((size_t)(t * 64) + rb0 + xr) * 512 + 256 + gc],
             ((unsigned long long)tagp << 32) | __float_as_uint((float)hnew * INV_S));
      if (t == 511) d_out[L * 32768 + (rb0 + xr) * 512 + 256 + gc] = hnew;
    }
    __syncthreads();   // protect h2i old-value reads before next-step P1 staging
    if (tid == 0) st64(&g_sent[L][dm][3][cg], ((unsigned long long)tagp << 32) | 1u);

    if (L == 0) {
      cz1a = nz1a; cz1b = nz1b; cg1x = ng1x; cz2a = nz2a; cz2b = nz2b; cg2x = ng2x;
    }
  }
#undef GATE
#undef STAGE8
#undef SPLIT3
}

// ------------------------------------------------------------------
extern "C" void kernel_launch(void* const* d_in, const int* in_sizes, int n_in,
                              void* d_out, int out_size, void* d_ws, size_t ws_size,
                              hipStream_t stream) {
  const int*   seq     = (const int*)d_in[0];
  const int*   lengths = (const int*)d_in[1];
  const float* emb     = (const float*)d_in[2];
  const float* Wz1     = (const float*)d_in[3];
  const float* bz1     = (const float*)d_in[4];
  const float* Wg1     = (const float*)d_in[5];
  const float* bg1     = (const float*)d_in[6];
  const float* Wz2     = (const float*)d_in[7];
  const float* bz2     = (const float*)d_in[8];
  const float* Wg2     = (const float*)d_in[9];
  const float* bg2     = (const float*)d_in[10];
  int* out = (int*)d_out;
  (void)in_sizes; (void)n_in; (void)out_size; (void)d_ws; (void)ws_size;

  bump_epoch<<<1, 1, 0, stream>>>();
  prep_x<<<3072, 256, 0, stream>>>(Wz1, bz1, Wg1, bg1, Wz2, bz2, Wg2, bg2, 0, out, 1);
  prep_x<<<3072, 256, 0, stream>>>(Wz1, bz1, Wg1, bg1, Wz2, bz2, Wg2, bg2, 1, out, 0);
  gemmx_kernel<<<dim3(256, 12), 256, 0, stream>>>(seq, emb);
  fused_kernel<<<112, 512, 0, stream>>>(Wz1, Wg1, Wz2, Wg2, lengths, out);
}

// Round 6
// 7787.635 us; speedup vs baseline: 1.5425x; 1.0956x over previous
//
#include <hip/hip_runtime.h>
#include <stdint.h>

// RevGRU encoder, MI355X.
// R12 == R11 resubmitted (container infra failure, no bench data; audit found no
// deadlock/correctness hazard). R10 (4-hop, sentinel gates, XCD colocation,
// early x1 issue; 8.25ms) with COALESCED rendezvous buffers: channels + g_h0s
// transposed to col-major [col][row], staging remapped so consecutive lanes
// touch consecutive addresses on both store and gather sides:
//   - channel stores: 16-lane groups write 128B contiguous (was 2KB stride/lane)
//   - channel gather: one 64B line per thread (col tid>>1, rows (tid&1)*8..+8)
//   - g_h0s: [t][col512][row64]; producer reads 128B/thread contiguous
// Protocol (tags/sentinels/gates/order) unchanged from the proven R8 structure;
// only addresses changed. Deposit+bf16-split fused into the stage pass.

typedef __attribute__((ext_vector_type(8))) short short8;
typedef __attribute__((ext_vector_type(4))) float floatx4;

#define MFMA16(a,b,c) __builtin_amdgcn_mfma_f32_16x16x32_bf16((a),(b),(c),0,0,0)

__device__ __forceinline__ short bf16_rne(float f) {
  uint32_t u = __float_as_uint(f);
  u += 0x7FFFu + ((u >> 16) & 1u);
  return (short)(u >> 16);
}
__device__ __forceinline__ float bf16f(short s) {
  return __uint_as_float(((uint32_t)(uint16_t)s) << 16);
}
__device__ __forceinline__ void st64(unsigned long long* p, unsigned long long v) {
  __hip_atomic_store(p, v, __ATOMIC_RELAXED, __HIP_MEMORY_SCOPE_AGENT);
}
__device__ __forceinline__ unsigned long long ld64(const unsigned long long* p) {
  return __hip_atomic_load(p, __ATOMIC_RELAXED, __HIP_MEMORY_SCOPE_AGENT);
}

#define SCALE_F 8388608.0f
#define INV_S   (1.0f/8388608.0f)

// ---- static device scratch ----
__device__ float g_X[50331648];            // X0: 32768 x 1536 (layer-0 x-projections)
__device__ short g_WTh[2][786432];         // per-layer x-proj weights, transposed, split hi
__device__ short g_WTl[2][786432];         // split lo
__device__ float g_biasL[2][1536];
__device__ unsigned long long g_ch[2][4][6][4096];  // channels, COL-MAJOR [col*16+row]
__device__ unsigned long long g_h0s[16777216];      // [t][col512][row64] tagged {tag, f32}
__device__ unsigned long long g_x1r[3145728];       // ring [t&31][row][1536] tagged {tag, f32}
__device__ unsigned long long g_sent[2][4][4][8];   // sentinels [L][dm][phase][cg]
__device__ unsigned g_epoch;

__global__ void bump_epoch() { g_epoch = g_epoch + 1u; }

// ------------------------------------------------------------------
__global__ void prep_x(const float* __restrict__ Wz1, const float* __restrict__ bz1,
                       const float* __restrict__ Wg1, const float* __restrict__ bg1,
                       const float* __restrict__ Wz2, const float* __restrict__ bz2,
                       const float* __restrict__ Wg2, const float* __restrict__ bg2,
                       int layer, int* __restrict__ d_out, int zero_extra) {
  int idx = blockIdx.x * 256 + threadIdx.x;   // grid covers 512*1536 exactly
  int k = idx / 1536;
  int c = idx - k * 1536;
  const float* W; const float* bb; int cc; int ncols;
  if (c < 512)       { W = Wz1; bb = bz1; cc = c;        ncols = 512; }
  else if (c < 768)  { W = Wg1; bb = bg1; cc = c - 512;  ncols = 256; }
  else if (c < 1280) { W = Wz2; bb = bz2; cc = c - 768;  ncols = 512; }
  else               { W = Wg2; bb = bg2; cc = c - 1280; ncols = 256; }
  float wv = W[(size_t)layer * 768 * ncols + (size_t)k * ncols + cc];
  short hi = bf16_rne(wv);
  short lo = bf16_rne(wv - bf16f(hi));
  g_WTh[layer][(size_t)c * 512 + k] = hi;
  g_WTl[layer][(size_t)c * 512 + k] = lo;
  if (k == 0) g_biasL[layer][c] = bb[layer * ncols + cc];
  if (zero_extra && idx < 6400) d_out[65536 + idx] = 0;   // saved[0] = h0 = zeros
}

// ------------------------------------------------------------------
__global__ __launch_bounds__(256)
void gemmx_kernel(const int* __restrict__ seq, const float* __restrict__ emb) {
  __shared__ float At[128][36];
  __shared__ short Bhi[128][40];
  __shared__ short Blo[128][40];
  __shared__ int toks[128];
  int tid = threadIdx.x;
  int r0 = blockIdx.x * 128;
  int c0 = blockIdx.y * 128;
  if (tid < 128) toks[tid] = seq[r0 + tid];
  int lane = tid & 63;
  int wid = tid >> 6;
  int wm = wid & 1, wn = wid >> 1;
  int lm = lane & 15, lq = lane >> 4;
  floatx4 zero4 = {0.f, 0.f, 0.f, 0.f};
  floatx4 acc[4][4];
#pragma unroll
  for (int a = 0; a < 4; ++a)
#pragma unroll
    for (int b = 0; b < 4; ++b) acc[a][b] = zero4;
  __syncthreads();
  int am = tid >> 1;
  int ah = (tid & 1) * 16;
  const float* arow = emb + (size_t)toks[am] * 512;
  const short* bh_base = g_WTh[0] + (size_t)(c0 + am) * 512;
  const short* bl_base = g_WTl[0] + (size_t)(c0 + am) * 512;
  for (int kb = 0; kb < 16; ++kb) {
    int k0 = kb * 32 + ah;
    float4 a0 = *(const float4*)(arow + k0);
    float4 a1 = *(const float4*)(arow + k0 + 4);
    float4 a2 = *(const float4*)(arow + k0 + 8);
    float4 a3 = *(const float4*)(arow + k0 + 12);
    short4 b0 = *(const short4*)(bh_base + k0);
    short4 b1 = *(const short4*)(bh_base + k0 + 4);
    short4 b2 = *(const short4*)(bh_base + k0 + 8);
    short4 b3 = *(const short4*)(bh_base + k0 + 12);
    short4 l0 = *(const short4*)(bl_base + k0);
    short4 l1 = *(const short4*)(bl_base + k0 + 4);
    short4 l2 = *(const short4*)(bl_base + k0 + 8);
    short4 l3 = *(const short4*)(bl_base + k0 + 12);
    __syncthreads();
    *(float4*)&At[am][ah]      = a0;
    *(float4*)&At[am][ah + 4]  = a1;
    *(float4*)&At[am][ah + 8]  = a2;
    *(float4*)&At[am][ah + 12] = a3;
    *(short4*)&Bhi[am][ah]      = b0;
    *(short4*)&Bhi[am][ah + 4]  = b1;
    *(short4*)&Bhi[am][ah + 8]  = b2;
    *(short4*)&Bhi[am][ah + 12] = b3;
    *(short4*)&Blo[am][ah]      = l0;
    *(short4*)&Blo[am][ah + 4]  = l1;
    *(short4*)&Blo[am][ah + 8]  = l2;
    *(short4*)&Blo[am][ah + 12] = l3;
    __syncthreads();
    short8 afh[4], afl[4];
#pragma unroll
    for (int mt = 0; mt < 4; ++mt) {
      const float* ap = &At[wm*64 + mt*16 + lm][lq*8];
#pragma unroll
      for (int j = 0; j < 8; ++j) {
        float v = ap[j];
        short hi = bf16_rne(v);
        afh[mt][j] = hi;
        afl[mt][j] = bf16_rne(v - bf16f(hi));
      }
    }
#pragma unroll
    for (int nt = 0; nt < 4; ++nt) {
      short8 bfh = *(short8*)&Bhi[wn*64 + nt*16 + lm][lq*8];
      short8 bfl = *(short8*)&Blo[wn*64 + nt*16 + lm][lq*8];
#pragma unroll
      for (int mt = 0; mt < 4; ++mt) {
        acc[mt][nt] = MFMA16(afh[mt], bfh, acc[mt][nt]);
        acc[mt][nt] = MFMA16(afl[mt], bfh, acc[mt][nt]);
        acc[mt][nt] = MFMA16(afh[mt], bfl, acc[mt][nt]);
      }
    }
  }
#pragma unroll
  for (int nt = 0; nt < 4; ++nt) {
    int gc = c0 + wn*64 + nt*16 + lm;
    float bv = g_biasL[0][gc];
#pragma unroll
    for (int mt = 0; mt < 4; ++mt) {
#pragma unroll
      for (int i = 0; i < 4; ++i) {
        int gr = r0 + wm*64 + mt*16 + lq*4 + i;
        g_X[(size_t)gr * 1536 + gc] = acc[mt][nt][i] + bv;
      }
    }
  }
}

// ------------------------------------------------------------------
__global__ __launch_bounds__(512, 1)
void fused_kernel(const float* __restrict__ Wz1g, const float* __restrict__ Wg1g,
                  const float* __restrict__ Wz2g, const float* __restrict__ Wg2g,
                  const int* __restrict__ lengths, int* __restrict__ d_out) {
  __shared__ int   h1i[16][260];
  __shared__ int   h2i[16][260];
  __shared__ short phi[16][264];
  __shared__ short pmi[16][264];
  __shared__ short plo[16][264];
  __shared__ float redbuf[2304];
  __shared__ int lens[16];
  __shared__ short ahs[16][520];
  __shared__ short als[16][520];

  int tid = threadIdx.x;
  int bid = blockIdx.x;
  int lane = tid & 63, wv = tid >> 6;   // 8 waves
  int lm = lane & 15, lq = lane >> 4;
  unsigned ep = g_epoch;

  if (bid >= 64) {
    // ================== role: X1 producer (48 WGs) ==================
    int xw = bid - 64;
    int r4 = xw & 3;        // row tile (16 rows) == dm of the L0 group it consumes
    int cs = xw >> 2;       // col slice (128 cols), 0..11
    int colx = cs * 128 + wv * 16 + lm;     // this lane's output column
    short8 bh[16], bl[16];
#pragma unroll
    for (int kf = 0; kf < 16; ++kf) {
      bh[kf] = *(const short8*)&g_WTh[1][(size_t)colx * 512 + kf * 32 + lq * 8];
      bl[kf] = *(const short8*)&g_WTl[1][(size_t)colx * 512 + kf * 32 + lq * 8];
    }
    float bvx = g_biasL[1][colx];

    for (int t = 0; t < 512; ++t) {
      unsigned tagt = (ep << 10) | (unsigned)(t + 1);
      // gate: wait until all 8 L0 WGs of domain r4 finished step t's P4
      if (tid < 8) {
        const unsigned long long* sp = &g_sent[0][r4][3][tid];
        while ((int)((unsigned)(ld64(sp) >> 32) - tagt) < 0) __builtin_amdgcn_s_sleep(1);
      }
      __syncthreads();
      // stage h0s[t]: thread tid takes col tid, rows r4*16..+16 (128B contiguous)
      {
        const unsigned long long* hp = &g_h0s[((size_t)t * 512 + tid) * 64 + r4 * 16];
        unsigned long long v[16];
        do { v[0] = ld64(hp); } while ((unsigned)(v[0] >> 32) != tagt);
#pragma unroll
        for (int i = 1; i < 16; ++i) v[i] = ld64(hp + i);
        unsigned pend = 0;
#pragma unroll
        for (int i = 1; i < 16; ++i)
          if ((unsigned)(v[i] >> 32) != tagt) pend |= 1u << i;
        while (pend) {
          __builtin_amdgcn_s_sleep(1);
#pragma unroll
          for (int i = 1; i < 16; ++i)
            if (pend & (1u << i)) {
              v[i] = ld64(hp + i);
              if ((unsigned)(v[i] >> 32) == tagt) pend &= ~(1u << i);
            }
        }
#pragma unroll
        for (int i = 0; i < 16; ++i) {
          float f = __uint_as_float((unsigned)v[i]);
          short hi = bf16_rne(f);
          ahs[i][tid] = hi;
          als[i][tid] = bf16_rne(f - bf16f(hi));
        }
      }
      __syncthreads();
      floatx4 acc = {0.f, 0.f, 0.f, 0.f};
#pragma unroll
      for (int kf = 0; kf < 16; ++kf) {
        short8 a0 = *(short8*)&ahs[lm][kf * 32 + lq * 8];
        short8 a1 = *(short8*)&als[lm][kf * 32 + lq * 8];
        acc = MFMA16(a0, bh[kf], acc);
        acc = MFMA16(a1, bh[kf], acc);
        acc = MFMA16(a0, bl[kf], acc);
      }
      // throttle: don't clobber ring slots L1 hasn't consumed (window 24 of 32)
      if (t >= 25) {
        if (tid < 4) {
          unsigned need = (ep << 10) | (unsigned)(t - 24);
          while ((unsigned)(ld64(&g_ch[1][tid][5][0]) >> 32) < need) __builtin_amdgcn_s_sleep(2);
        }
      }
      __syncthreads();
#pragma unroll
      for (int i = 0; i < 4; ++i) {
        int row = r4 * 16 + lq * 4 + i;
        st64(&g_x1r[((size_t)(t & 31) * 64 + row) * 1536 + colx],
             ((unsigned long long)tagt << 32) | __float_as_uint(acc[i] + bvx));
      }
      __syncthreads();   // before next stage overwrites ahs/als
    }
    return;
  }

  // ================== role: scan (layer L), 32 WGs each ==================
  // XCD colocation: the 8 cooperating WGs of a (L,dm) group share bid%8.
  int grp = bid & 7;
  int cg  = bid >> 3;     // column group 0..7
  int L   = grp >> 2;
  int dm  = grp & 3;      // batch domain 0..3
  int rb0 = dm * 16;
  unsigned long long (*ch)[4096] = g_ch[L][dm];

  if (tid < 16) lens[tid] = lengths[rb0 + tid];
  for (int i = tid; i < 16 * 260; i += 512) { ((int*)h1i)[i] = 0; ((int*)h2i)[i] = 0; }

  // ---- preload recurrent-weight B-frags into registers (split-bf16) ----
  short8 wz1a[4], wz1b[4], wz1c[4], wz2a[4], wz2b[4], wz2c[4];
  short8 wg1a[2], wg1b[2], wg2a[2], wg2b[2];
  {
    int nt = wv & 3, kh = wv >> 2;
    int colz = cg * 64 + nt * 16 + lm;
    const float* W1 = Wz1g + (size_t)L * 768 * 512 + (size_t)512 * 512 + colz;
    const float* W2 = Wz2g + (size_t)L * 768 * 512 + (size_t)512 * 512 + colz;
#pragma unroll
    for (int ks = 0; ks < 4; ++ks) {
      int k0 = kh * 128 + ks * 32 + lq * 8;
      short8 t0, t1, t2, u0, u1, u2;
#pragma unroll
      for (int j = 0; j < 8; ++j) {
        float v = W1[(size_t)(k0 + j) * 512] * INV_S;   // pre-scale: A is raw int h
        short a0 = bf16_rne(v); float r1 = v - bf16f(a0);
        short a1 = bf16_rne(r1); float r2 = r1 - bf16f(a1);
        t0[j] = a0; t1[j] = a1; t2[j] = bf16_rne(r2);
        float v2 = W2[(size_t)(k0 + j) * 512] * INV_S;
        short d0 = bf16_rne(v2); float s1 = v2 - bf16f(d0);
        short d1 = bf16_rne(s1); float s2 = s1 - bf16f(d1);
        u0[j] = d0; u1[j] = d1; u2[j] = bf16_rne(s2);
      }
      wz1a[ks] = t0; wz1b[ks] = t1; wz1c[ks] = t2;
      wz2a[ks] = u0; wz2b[ks] = u1; wz2c[ks] = u2;
    }
    int ntg = wv & 1, kq = wv >> 1;
    int colg = cg * 32 + ntg * 16 + lm;
    const float* G1 = Wg1g + (size_t)L * 768 * 256 + (size_t)512 * 256 + colg;
    const float* G2 = Wg2g + (size_t)L * 768 * 256 + (size_t)512 * 256 + colg;
#pragma unroll
    for (int ks = 0; ks < 2; ++ks) {
      int k0 = kq * 64 + ks * 32 + lq * 8;
      short8 t0, t1, u0, u1;
#pragma unroll
      for (int j = 0; j < 8; ++j) {
        float v = G1[(size_t)(k0 + j) * 256];
        short a0 = bf16_rne(v);
        t0[j] = a0; t1[j] = bf16_rne(v - bf16f(a0));
        float v2 = G2[(size_t)(k0 + j) * 256];
        short d0 = bf16_rne(v2);
        u0[j] = d0; u1[j] = bf16_rne(v2 - bf16f(d0));
      }
      wg1a[ks] = t0; wg1b[ks] = t1; wg2a[ks] = u0; wg2b[ks] = u1;
    }
  }
  __syncthreads();

  int xr = tid & 15, xc = tid >> 4;           // compute mapping (unchanged)
  int scc = tid >> 1, sh = (tid & 1) << 3;    // stage mapping: col scc, rows sh..sh+8

  // x1-ring column offsets (loop-invariant)
  int xo0 = cg * 64 + 2 * xc;          // z1 pair
  int xo1 = 512 + cg * 32 + xc;        // g1
  int xo2 = 768 + cg * 64 + 2 * xc;    // z2 pair
  int xo3 = 1280 + cg * 32 + xc;       // g2

  auto ldx = [&](int tt, float& za, float& zb, float& g1x, float& ya, float& yb, float& g2x) {
    const float* base = g_X + (size_t)(tt * 64 + rb0 + xr) * 1536;
    float2 v1 = *(const float2*)(base + cg * 64 + 2 * xc);
    za = v1.x; zb = v1.y;
    g1x = base[512 + cg * 32 + xc];
    float2 v2 = *(const float2*)(base + 768 + cg * 64 + 2 * xc);
    ya = v2.x; yb = v2.y;
    g2x = base[1280 + cg * 32 + xc];
  };
  float cz1a = 0.f, cz1b = 0.f, cg1x = 0.f, cz2a = 0.f, cz2b = 0.f, cg2x = 0.f;
  if (L == 0) ldx(0, cz1a, cz1b, cg1x, cz2a, cz2b, cg2x);

#define GATE(PH, NEED)                                                         \
  {                                                                            \
    if (tid < 8) {                                                             \
      const unsigned long long* sp_ = &g_sent[L][dm][PH][tid];                 \
      while ((int)((unsigned)(ld64(sp_) >> 32) - (NEED)) < 0)                  \
        __builtin_amdgcn_s_sleep(1);                                           \
    }                                                                          \
    __syncthreads();                                                           \
  }

// stage 8 values: col scc, rows sh..sh+8 -> one 64B line per thread
#define STAGE8(CHIDX, EXP, DEPOSIT)                                            \
  {                                                                            \
    const unsigned long long* cp_ = &ch[CHIDX][scc * 16 + sh];                 \
    unsigned long long v_[8];                                                  \
    do { v_[0] = ld64(cp_); } while ((unsigned)(v_[0] >> 32) != (EXP));        \
    _Pragma("unroll")                                                          \
    for (int i_ = 1; i_ < 8; ++i_) v_[i_] = ld64(cp_ + i_);                    \
    unsigned pend_ = 0;                                                        \
    _Pragma("unroll")                                                          \
    for (int i_ = 1; i_ < 8; ++i_)                                             \
      if ((unsigned)(v_[i_] >> 32) != (EXP)) pend_ |= 1u << i_;                \
    while (pend_) {                                                            \
      __builtin_amdgcn_s_sleep(1);                                             \
      _Pragma("unroll")                                                        \
      for (int i_ = 1; i_ < 8; ++i_)                                           \
        if (pend_ & (1u << i_)) {                                              \
          v_[i_] = ld64(cp_ + i_);                                             \
          if ((unsigned)(v_[i_] >> 32) == (EXP)) pend_ &= ~(1u << i_);         \
        }                                                                      \
    }                                                                          \
    _Pragma("unroll")                                                          \
    for (int i_ = 0; i_ < 8; ++i_) { DEPOSIT; }                                \
  }

// deposit raw h + 3-way bf16 split (fused)
#define DEP_SPLIT(HARR)                                                        \
  { int hv_ = (int)(unsigned)v_[i_];                                           \
    HARR[sh + i_][scc] = hv_;                                                  \
    float fv_ = (float)hv_;                                                    \
    short a0_ = bf16_rne(fv_); float r1_ = fv_ - bf16f(a0_);                   \
    short a1_ = bf16_rne(r1_);                                                 \
    phi[sh + i_][scc] = a0_; pmi[sh + i_][scc] = a1_;                          \
    plo[sh + i_][scc] = bf16_rne(r1_ - bf16f(a1_)); }

#define DEP_R()                                                                \
  { unsigned pl_ = (unsigned)v_[i_];                                           \
    phi[sh + i_][scc] = (short)(pl_ >> 16);                                    \
    plo[sh + i_][scc] = (short)(pl_ & 0xFFFFu); }

// t==0 split of zeroed h2i (same element coverage as the fused path)
#define SPLIT3Z(SRC)                                                           \
  {                                                                            \
    _Pragma("unroll")                                                          \
    for (int i_ = 0; i_ < 8; ++i_) {                                           \
      float v = (float)SRC[sh + i_][scc];                                      \
      short a0 = bf16_rne(v); float r1 = v - bf16f(a0);                        \
      short a1 = bf16_rne(r1);                                                 \
      phi[sh + i_][scc] = a0; pmi[sh + i_][scc] = a1;                          \
      plo[sh + i_][scc] = bf16_rne(r1 - bf16f(a1));                            \
    }                                                                          \
  }

  for (int t = 0; t < 512; ++t) {
    unsigned tagp = (ep << 10) | (unsigned)(t + 1);

    float nz1a, nz1b, ng1x, nz2a, nz2b, ng2x;
    if (L == 0) {
      int tn = (t + 1 < 512) ? t + 1 : t;
      ldx(tn, nz1a, nz1b, ng1x, nz2a, nz2b, ng2x);   // prefetch next step's X0
    }

    // L1: issue this step's 6 x1-ring loads early (producers run ahead; tags
    // usually already valid). Verified at the original use points below.
    const unsigned long long* xb = nullptr;
    unsigned long long x0v = 0, x1v = 0, x2v = 0, x3v = 0, x4v = 0, x5v = 0;
    if (L == 1) {
      xb = &g_x1r[((size_t)((t & 31) * 64) + rb0 + xr) * 1536];
      x0v = ld64(xb + xo0); x1v = ld64(xb + xo0 + 1);
      x2v = ld64(xb + xo1);
      x3v = ld64(xb + xo2); x4v = ld64(xb + xo2 + 1);
      x5v = ld64(xb + xo3);
    }
    auto vfy = [&](unsigned long long v, const unsigned long long* p) -> float {
      while ((unsigned)(v >> 32) != tagp) { __builtin_amdgcn_s_sleep(1); v = ld64(p); }
      return __uint_as_float((unsigned)v);
    };

    // ================= P1: z1 =================
    if (t > 0) {
      GATE(3, (ep << 10) | (unsigned)t);
      STAGE8(5, (ep << 10) | (unsigned)t, DEP_SPLIT(h2i));
    } else {
      SPLIT3Z(h2i);
    }
    __syncthreads();
    {
      int nt = wv & 3, kh = wv >> 2;
      floatx4 acc = {0.f, 0.f, 0.f, 0.f};
#pragma unroll
      for (int ks = 0; ks < 4; ++ks) {
        int k0 = kh * 128 + ks * 32 + lq * 8;
        short8 a0 = *(short8*)&phi[lm][k0];
        short8 a1 = *(short8*)&pmi[lm][k0];
        short8 a2 = *(short8*)&plo[lm][k0];
        acc = MFMA16(a0, wz1a[ks], acc);
        acc = MFMA16(a0, wz1b[ks], acc);
        acc = MFMA16(a1, wz1a[ks], acc);
        acc = MFMA16(a1, wz1b[ks], acc);
        acc = MFMA16(a0, wz1c[ks], acc);
        acc = MFMA16(a2, wz1a[ks], acc);
      }
#pragma unroll
      for (int i = 0; i < 4; ++i) redbuf[kh * 1088 + (lq * 4 + i) * 68 + nt * 16 + lm] = acc[i];
    }
    __syncthreads();
    {
      if (L == 1) { cz1a = vfy(x0v, xb + xo0); cz1b = vfy(x1v, xb + xo0 + 1); }
#pragma unroll
      for (int u = 0; u < 2; ++u) {
        int cc = 2 * xc + u;
        float pre = redbuf[xr * 68 + cc] + redbuf[1088 + xr * 68 + cc] + (u ? cz1b : cz1a);
        float s = 1.0f / (1.0f + expf(-pre));
        int gcol = cg * 64 + cc;
        if (gcol < 256) {
          float qf = floorf((0.875f * s + 0.125f) * 1024.0f);
          int qi = (int)qf; qi = qi < 1 ? 1 : (qi > 1024 ? 1024 : qi);
          st64(&ch[0][gcol * 16 + xr], ((unsigned long long)tagp << 32) | (unsigned)qi);
        } else {
          int rc = gcol - 256;
          float p = s * ((float)h2i[xr][rc] * INV_S);
          short p0 = bf16_rne(p);
          short p1s = bf16_rne(p - bf16f(p0));
          unsigned pay = ((unsigned)(unsigned short)p0 << 16) | (unsigned)(unsigned short)p1s;
          st64(&ch[1][rc * 16 + xr], ((unsigned long long)tagp << 32) | pay);
        }
      }
    }
    __syncthreads();   // drain P1 stores (compiler emits vmcnt(0) before barrier)
    if (tid == 0) st64(&g_sent[L][dm][0][cg], ((unsigned long long)tagp << 32) | 1u);
    GATE(0, tagp);

    // ================= P2: g1 + h1 update =================
    int qv;
    STAGE8(1, tagp, DEP_R());
    {
      const unsigned long long* qp = &ch[0][(cg * 32 + xc) * 16 + xr];
      unsigned long long q64;
      do { q64 = ld64(qp); } while ((unsigned)(q64 >> 32) != tagp);
      qv = (int)(unsigned)q64;
    }
    __syncthreads();
    {
      int ntg = wv & 1, kq = wv >> 1;
      floatx4 acc = {0.f, 0.f, 0.f, 0.f};
#pragma unroll
      for (int ks = 0; ks < 2; ++ks) {
        int k0 = kq * 64 + ks * 32 + lq * 8;
        short8 a0 = *(short8*)&phi[lm][k0];
        short8 a1 = *(short8*)&plo[lm][k0];
        acc = MFMA16(a0, wg1a[ks], acc);
        acc = MFMA16(a1, wg1a[ks], acc);
        acc = MFMA16(a0, wg1b[ks], acc);
      }
#pragma unroll
      for (int i = 0; i < 4; ++i) redbuf[kq * 576 + (lq * 4 + i) * 36 + ntg * 16 + lm] = acc[i];
    }
    __syncthreads();
    {
      if (L == 1) cg1x = vfy(x2v, xb + xo1);
      float pre = redbuf[xr * 36 + xc] + redbuf[576 + xr * 36 + xc]
                + redbuf[1152 + xr * 36 + xc] + redbuf[1728 + xr * 36 + xc] + cg1x;
      float g = tanhf(pre);
      int gc = cg * 32 + xc;
      int q = qv;
      int hold = h1i[xr][gc];
      float zf = (float)q * (1.0f / 1024.0f);
      int ni = (int)rintf((1.0f - zf) * g * SCALE_F);
      int hnew = (hold >> 10) * q + (((hold & 1023) * q) >> 10) + ni;
      if (t >= lens[xr]) hnew = hold;
      st64(&ch[2][gc * 16 + xr], ((unsigned long long)tagp << 32) | (unsigned)hnew);
      if (L == 0)
        st64(&g_h0s[((size_t)t * 512 + gc) * 64 + rb0 + xr],
             ((unsigned long long)tagp << 32) | __float_as_uint((float)hnew * INV_S));
      else if (gc < 100) d_out[65536 + (t + 1) * 6400 + (rb0 + xr) * 100 + gc] = hnew;
      if (t == 511) d_out[L * 32768 + (rb0 + xr) * 512 + gc] = hnew;
    }
    __syncthreads();   // protect h1i old-value reads before P3 staging overwrites
    if (tid == 0) st64(&g_sent[L][dm][1][cg], ((unsigned long long)tagp << 32) | 1u);
    GATE(1, tagp);

    // ================= P3: z2 =================
    STAGE8(2, tagp, DEP_SPLIT(h1i));
    __syncthreads();
    {
      int nt = wv & 3, kh = wv >> 2;
      floatx4 acc = {0.f, 0.f, 0.f, 0.f};
#pragma unroll
      for (int ks = 0; ks < 4; ++ks) {
        int k0 = kh * 128 + ks * 32 + lq * 8;
        short8 a0 = *(short8*)&phi[lm][k0];
        short8 a1 = *(short8*)&pmi[lm][k0];
        short8 a2 = *(short8*)&plo[lm][k0];
        acc = MFMA16(a0, wz2a[ks], acc);
        acc = MFMA16(a0, wz2b[ks], acc);
        acc = MFMA16(a1, wz2a[ks], acc);
        acc = MFMA16(a1, wz2b[ks], acc);
        acc = MFMA16(a0, wz2c[ks], acc);
        acc = MFMA16(a2, wz2a[ks], acc);
      }
#pragma unroll
      for (int i = 0; i < 4; ++i) redbuf[kh * 1088 + (lq * 4 + i) * 68 + nt * 16 + lm] = acc[i];
    }
    __syncthreads();
    {
      if (L == 1) { cz2a = vfy(x3v, xb + xo2); cz2b = vfy(x4v, xb + xo2 + 1); }
#pragma unroll
      for (int u = 0; u < 2; ++u) {
        int cc = 2 * xc + u;
        float pre = redbuf[xr * 68 + cc] + redbuf[1088 + xr * 68 + cc] + (u ? cz2b : cz2a);
        float s = 1.0f / (1.0f + expf(-pre));
        int gcol = cg * 64 + cc;
        if (gcol < 256) {
          float qf = floorf((0.875f * s + 0.125f) * 1024.0f);
          int qi = (int)qf; qi = qi < 1 ? 1 : (qi > 1024 ? 1024 : qi);
          st64(&ch[3][gcol * 16 + xr], ((unsigned long long)tagp << 32) | (unsigned)qi);
        } else {
          int rc = gcol - 256;
          float p = s * ((float)h1i[xr][rc] * INV_S);
          short p0 = bf16_rne(p);
          short p1s = bf16_rne(p - bf16f(p0));
          unsigned pay = ((unsigned)(unsigned short)p0 << 16) | (unsigned)(unsigned short)p1s;
          st64(&ch[4][rc * 16 + xr], ((unsigned long long)tagp << 32) | pay);
        }
      }
    }
    __syncthreads();   // drain P3 stores
    if (tid == 0) st64(&g_sent[L][dm][2][cg], ((unsigned long long)tagp << 32) | 1u);
    GATE(2, tagp);

    // ================= P4: g2 + h2 update =================
    int qv2;
    STAGE8(4, tagp, DEP_R());
    {
      const unsigned long long* qp = &ch[3][(cg * 32 + xc) * 16 + xr];
      unsigned long long q64;
      do { q64 = ld64(qp); } while ((unsigned)(q64 >> 32) != tagp);
      qv2 = (int)(unsigned)q64;
    }
    __syncthreads();
    {
      int ntg = wv & 1, kq = wv >> 1;
      floatx4 acc = {0.f, 0.f, 0.f, 0.f};
#pragma unroll
      for (int ks = 0; ks < 2; ++ks) {
        int k0 = kq * 64 + ks * 32 + lq * 8;
        short8 a0 = *(short8*)&phi[lm][k0];
        short8 a1 = *(short8*)&plo[lm][k0];
        acc = MFMA16(a0, wg2a[ks], acc);
        acc = MFMA16(a1, wg2a[ks], acc);
        acc = MFMA16(a0, wg2b[ks], acc);
      }
#pragma unroll
      for (int i = 0; i < 4; ++i) redbuf[kq * 576 + (lq * 4 + i) * 36 + ntg * 16 + lm] = acc[i];
    }
    __syncthreads();
    {
      if (L == 1) cg2x = vfy(x5v, xb + xo3);
      float pre = redbuf[xr * 36 + xc] + redbuf[576 + xr * 36 + xc]
                + redbuf[1152 + xr * 36 + xc] + redbuf[1728 + xr * 36 + xc] + cg2x;
      float g = tanhf(pre);
      int gc = cg * 32 + xc;
      int q = qv2;
      int hold = h2i[xr][gc];
      float zf = (float)q * (1.0f / 1024.0f);
      int ni = (int)rintf((1.0f - zf) * g * SCALE_F);
      int hnew = (hold >> 10) * q + (((hold & 1023) * q) >> 10) + ni;
      if (t >= lens[xr]) hnew = hold;
      st64(&ch[5][gc * 16 + xr], ((unsigned long long)tagp << 32) | (unsigned)hnew);
      if (L == 0)
        st64(&g_h0s[((size_t)t * 512 + 256 + gc) * 64 + rb0 + xr],
             ((unsigned long long)tagp << 32) | __float_as_uint((float)hnew * INV_S));
      if (t == 511) d_out[L * 32768 + (rb0 + xr) * 512 + 256 + gc] = hnew;
    }
    __syncthreads();   // protect h2i old-value reads before next-step P1 staging
    if (tid == 0) st64(&g_sent[L][dm][3][cg], ((unsigned long long)tagp << 32) | 1u);

    if (L == 0) {
      cz1a = nz1a; cz1b = nz1b; cg1x = ng1x; cz2a = nz2a; cz2b = nz2b; cg2x = ng2x;
    }
  }
#undef GATE
#undef STAGE8
#undef DEP_SPLIT
#undef DEP_R
#undef SPLIT3Z
}

// ------------------------------------------------------------------
extern "C" void kernel_launch(void* const* d_in, const int* in_sizes, int n_in,
                              void* d_out, int out_size, void* d_ws, size_t ws_size,
                              hipStream_t stream) {
  const int*   seq     = (const int*)d_in[0];
  const int*   lengths = (const int*)d_in[1];
  const float* emb     = (const float*)d_in[2];
  const float* Wz1     = (const float*)d_in[3];
  const float* bz1     = (const float*)d_in[4];
  const float* Wg1     = (const float*)d_in[5];
  const float* bg1     = (const float*)d_in[6];
  const float* Wz2     = (const float*)d_in[7];
  const float* bz2     = (const float*)d_in[8];
  const float* Wg2     = (const float*)d_in[9];
  const float* bg2     = (const float*)d_in[10];
  int* out = (int*)d_out;
  (void)in_sizes; (void)n_in; (void)out_size; (void)d_ws; (void)ws_size;

  bump_epoch<<<1, 1, 0, stream>>>();
  prep_x<<<3072, 256, 0, stream>>>(Wz1, bz1, Wg1, bg1, Wz2, bz2, Wg2, bg2, 0, out, 1);
  prep_x<<<3072, 256, 0, stream>>>(Wz1, bz1, Wg1, bg1, Wz2, bz2, Wg2, bg2, 1, out, 0);
  gemmx_kernel<<<dim3(256, 12), 256, 0, stream>>>(seq, emb);
  fused_kernel<<<112, 512, 0, stream>>>(Wz1, Wg1, Wz2, Wg2, lengths, out);
}